// Round 3
// baseline (2093.063 us; speedup 1.0000x reference)
//
#include <hip/hip_runtime.h>
#include <hip/hip_bf16.h>

typedef __hip_bfloat16 bf16;
typedef __attribute__((ext_vector_type(4))) float f32x4;
typedef __attribute__((ext_vector_type(8))) short s16x8;
typedef unsigned int u32;
typedef unsigned short u16;

#define B_ 16
#define T_ 4096
#define D_ 768
#define S_ 768
#define NS 16
#define NIT 9
#define NCHUNK 16
#define TCH 256
#define EPS 1e-8f
#define SCALE 0.036084391824351615f  /* 768^-0.5 */

__device__ __forceinline__ void gld16(const void* g, void* l) {
    __builtin_amdgcn_global_load_lds((const __attribute__((address_space(1))) u32*)g,
                                     (__attribute__((address_space(3))) u32*)l, 16, 0, 0);
}

__device__ __forceinline__ u16 bfbits(float x) {
    bf16 h = __float2bfloat16(x);
    return *reinterpret_cast<u16*>(&h);
}

// ---------------------------------------------------------------------------
// All weight conversions in one launch. wkv = [Wk rows; Wv rows] (1536 x 768).
__global__ void __launch_bounds__(256) cvt_all_kernel(
    const float* __restrict__ wq, const float* __restrict__ wk, const float* __restrict__ wv,
    const float* __restrict__ gwih, const float* __restrict__ gwhh,
    const float* __restrict__ w1, const float* __restrict__ w2,
    bf16* __restrict__ wq_b, bf16* __restrict__ wkv_b,
    bf16* __restrict__ gwih_b, bf16* __restrict__ gwhh_b,
    bf16* __restrict__ w1_b, bf16* __restrict__ w2_b)
{
    int i = blockIdx.x * 256 + threadIdx.x;
    const int NW = 589824, NG = 1769472, NM = 2359296;
    if (i < NW) { wq_b[i] = __float2bfloat16(wq[i]); return; }
    i -= NW;
    if (i < NW) { wkv_b[i] = __float2bfloat16(wk[i]); return; }
    i -= NW;
    if (i < NW) { wkv_b[NW + i] = __float2bfloat16(wv[i]); return; }
    i -= NW;
    if (i < NG) { gwih_b[i] = __float2bfloat16(gwih[i]); return; }
    i -= NG;
    if (i < NG) { gwhh_b[i] = __float2bfloat16(gwhh[i]); return; }
    i -= NG;
    if (i < NM) { w1_b[i] = __float2bfloat16(w1[i]); return; }
    i -= NM;
    w2_b[i] = __float2bfloat16(w2[i]);
}

// ---------------------------------------------------------------------------
// LayerNorm over rows of width 768, fp32 in -> bf16 out. One 256-thread block per row.
__global__ void __launch_bounds__(256) ln768_kernel(
    const float* __restrict__ x, const float* __restrict__ g,
    const float* __restrict__ bta, bf16* __restrict__ out)
{
    int row = blockIdx.x;
    int tid = threadIdx.x;
    const float* xr = x + (size_t)row * 768;
    float v0 = xr[tid], v1 = xr[tid + 256], v2 = xr[tid + 512];
    float s = v0 + v1 + v2;
    int lane = tid & 63, wid = tid >> 6;
    #pragma unroll
    for (int off = 32; off; off >>= 1) s += __shfl_down(s, off);
    __shared__ float red[4];
    __shared__ float sh_mu, sh_rs;
    if (lane == 0) red[wid] = s;
    __syncthreads();
    if (tid == 0) sh_mu = (red[0] + red[1] + red[2] + red[3]) * (1.f / 768.f);
    __syncthreads();
    float mu = sh_mu;
    float d0 = v0 - mu, d1 = v1 - mu, d2 = v2 - mu;
    float q = d0 * d0 + d1 * d1 + d2 * d2;
    #pragma unroll
    for (int off = 32; off; off >>= 1) q += __shfl_down(q, off);
    if (lane == 0) red[wid] = q;
    __syncthreads();
    if (tid == 0) sh_rs = rsqrtf((red[0] + red[1] + red[2] + red[3]) * (1.f / 768.f) + 1e-5f);
    __syncthreads();
    float rs = sh_rs;
    bf16* orow = out + (size_t)row * 768;
    orow[tid]       = __float2bfloat16(d0 * rs * g[tid]       + bta[tid]);
    orow[tid + 256] = __float2bfloat16(d1 * rs * g[tid + 256] + bta[tid + 256]);
    orow[tid + 512] = __float2bfloat16(d2 * rs * g[tid + 512] + bta[tid + 512]);
}

// ---------------------------------------------------------------------------
// 128x128 tiled NT GEMM, BK=64, double-buffered global_load_lds staging.
// grid: x = N/128 (fast, shares A panel), y = M/128.
__global__ void __launch_bounds__(256) gemm128_kernel(
    const bf16* __restrict__ A, const bf16* __restrict__ Bm, bf16* __restrict__ Cb,
    int M, int N, int K)
{
    __shared__ bf16 As[2][128 * 64];
    __shared__ bf16 Bs[2][128 * 64];
    int tid = threadIdx.x, lane = tid & 63, wid = tid >> 6;
    int bm0 = blockIdx.y * 128, bn0 = blockIdx.x * 128;
    int wr = wid >> 1, wc = wid & 1;
    int g = lane >> 4, r15 = lane & 15;
    const f32x4 vzero = {0.f, 0.f, 0.f, 0.f};
    f32x4 acc[4][4];
    #pragma unroll
    for (int m = 0; m < 4; ++m)
        #pragma unroll
        for (int n = 0; n < 4; ++n) acc[m][n] = vzero;

    auto stage = [&](int buf, int kt) {
        #pragma unroll
        for (int i = 0; i < 4; ++i) {
            int sa = wid * 64 + i * 256;
            int o = (sa + lane) * 16;
            int r = o >> 7, cb = o & 127;
            int cbs = cb ^ ((r & 7) << 4);
            gld16(A + (size_t)(bm0 + r) * K + kt + (cbs >> 1),
                  (char*)As[buf] + (size_t)sa * 16);
        }
        #pragma unroll
        for (int i = 0; i < 4; ++i) {
            int sa = wid * 64 + i * 256;
            int o = (sa + lane) * 16;
            int r = o >> 7, cb = o & 127;
            int cbs = cb ^ ((r & 7) << 4);
            gld16(Bm + (size_t)(bn0 + r) * K + kt + (cbs >> 1),
                  (char*)Bs[buf] + (size_t)sa * 16);
        }
    };

    stage(0, 0);
    asm volatile("s_waitcnt vmcnt(0)" ::: "memory");
    __syncthreads();
    int nk = K / 64;
    for (int t = 0; t < nk; ++t) {
        int cur = t & 1;
        if (t + 1 < nk) stage(cur ^ 1, (t + 1) * 64);
        #pragma unroll
        for (int kk = 0; kk < 64; kk += 32) {
            s16x8 af[4], bfr[4];
            #pragma unroll
            for (int m = 0; m < 4; ++m) {
                int r = wr * 64 + m * 16 + r15;
                int p = r * 128 + ((kk * 2 + g * 16) ^ ((r & 7) << 4));
                af[m] = *(const s16x8*)((const char*)As[cur] + p);
            }
            #pragma unroll
            for (int n = 0; n < 4; ++n) {
                int r = wc * 64 + n * 16 + r15;
                int p = r * 128 + ((kk * 2 + g * 16) ^ ((r & 7) << 4));
                bfr[n] = *(const s16x8*)((const char*)Bs[cur] + p);
            }
            #pragma unroll
            for (int m = 0; m < 4; ++m)
                #pragma unroll
                for (int n = 0; n < 4; ++n)
                    acc[m][n] = __builtin_amdgcn_mfma_f32_16x16x32_bf16(af[m], bfr[n], acc[m][n], 0, 0, 0);
        }
        asm volatile("s_waitcnt vmcnt(0)" ::: "memory");
        __syncthreads();
    }
    #pragma unroll
    for (int m = 0; m < 4; ++m) {
        int cm = bm0 + wr * 64 + m * 16 + g * 4;
        #pragma unroll
        for (int n = 0; n < 4; ++n) {
            int cn = bn0 + wc * 64 + n * 16 + r15;
            #pragma unroll
            for (int j = 0; j < 4; ++j)
                Cb[(size_t)(cm + j) * N + cn] = __float2bfloat16(acc[m][n][j]);
        }
    }
}

// ---------------------------------------------------------------------------
// Transpose v-part of kv [B,T,1536(cols 768..)] -> vT [B,768,T], plus vsum atomic.
__global__ void __launch_bounds__(256) transpose_vsum_kernel(
    const bf16* __restrict__ kv, bf16* __restrict__ vt, float* __restrict__ vsum)
{
    __shared__ bf16 tile[32][33];
    int b = blockIdx.z;
    int t0 = blockIdx.x * 32, d0 = blockIdx.y * 32;
    int tx = threadIdx.x & 31, ty = threadIdx.x >> 5;
    const bf16* vb = kv + (size_t)b * T_ * 1536 + 768;
    bf16* vtb = vt + (size_t)b * S_ * T_;
    #pragma unroll
    for (int r = ty; r < 32; r += 8)
        tile[r][tx] = vb[(size_t)(t0 + r) * 1536 + d0 + tx];
    __syncthreads();
    #pragma unroll
    for (int r = ty; r < 32; r += 8)
        vtb[(size_t)(d0 + r) * T_ + t0 + tx] = tile[tx][r];
    if (threadIdx.x < 32) {
        float s = 0.f;
        #pragma unroll
        for (int r = 0; r < 32; ++r) s += __bfloat162float(tile[r][threadIdx.x]);
        atomicAdd(vsum + b * 768 + d0 + threadIdx.x, s);
    }
}

// ---------------------------------------------------------------------------
__global__ void init_slots_kernel(const float* __restrict__ si,
                                  float* __restrict__ slots, bf16* __restrict__ slots_bf)
{
    int idx = blockIdx.x * 256 + threadIdx.x;  // 256*768
    float v = si[idx % (NS * S_)];
    slots[idx] = v;
    slots_bf[idx] = __float2bfloat16(v);
}

// ---------------------------------------------------------------------------
// Fused LN(rows of 16) + NT GEMM: out[m, cn] = act(LN(x)[m,:] @ W[cn,:] + bias[cn])
// grid (M/16, N/64). W: [N][768] bf16. out bf16 [M][N].
__global__ void __launch_bounds__(256) ln_gemm_kernel(
    const float* __restrict__ xin, const float* __restrict__ gam, const float* __restrict__ bet,
    const bf16* __restrict__ W, const float* __restrict__ bias,
    bf16* __restrict__ out, int N, int relu)
{
    __shared__ bf16 As[16 * 768];  // rows 1536B, XOR-swizzled
    int tid = threadIdx.x;
    int bx = blockIdx.x, bn0 = blockIdx.y * 64;
    int row = tid >> 4, li = tid & 15;
    const float* xr = xin + (size_t)(bx * 16 + row) * 768;
    float vals[48];
    float s = 0.f;
    #pragma unroll
    for (int i = 0; i < 48; ++i) { vals[i] = xr[li + i * 16]; s += vals[i]; }
    #pragma unroll
    for (int m = 1; m < 16; m <<= 1) s += __shfl_xor(s, m);
    float mu = s * (1.f / 768.f);
    float q = 0.f;
    #pragma unroll
    for (int i = 0; i < 48; ++i) { float d = vals[i] - mu; q += d * d; }
    #pragma unroll
    for (int m = 1; m < 16; m <<= 1) q += __shfl_xor(q, m);
    float rs = rsqrtf(q * (1.f / 768.f) + 1e-5f);
    #pragma unroll
    for (int i = 0; i < 48; ++i) {
        int c = li + i * 16;
        float v = (vals[i] - mu) * rs * gam[c] + bet[c];
        *(u16*)((char*)As + row * 1536 + ((c * 2) ^ ((row & 7) << 4))) = bfbits(v);
    }
    __syncthreads();
    int lane = tid & 63, wid = tid >> 6;
    int g = lane >> 4, s15 = lane & 15;
    int cn = bn0 + wid * 16 + s15;
    f32x4 acc = {0.f, 0.f, 0.f, 0.f};
    for (int kk = 0; kk < 768; kk += 32) {
        s16x8 af = *(const s16x8*)((const char*)As + s15 * 1536 + ((kk * 2 + g * 16) ^ ((s15 & 7) << 4)));
        s16x8 bf_ = *(const s16x8*)(W + (size_t)cn * 768 + kk + g * 8);
        acc = __builtin_amdgcn_mfma_f32_16x16x32_bf16(af, bf_, acc, 0, 0, 0);
    }
    float bv = bias ? bias[cn] : 0.f;
    #pragma unroll
    for (int j = 0; j < 4; ++j) {
        float val = acc[j] + bv;
        if (relu) val = fmaxf(val, 0.f);
        out[(size_t)(bx * 16 + g * 4 + j) * N + cn] = __float2bfloat16(val);
    }
}

// ---------------------------------------------------------------------------
// Fused attention: per (batch, 256-t chunk): dotsT = k@q^T, softmax over slots,
// partial U^T += vT@a^T, partial rowsum. All operands direct-global except the
// tiny a-exchange tile. 4 waves, each owns 16 t-rows per 64-t window.
__global__ void __launch_bounds__(256) fused_attn_kernel(
    const bf16* __restrict__ q_bf, const bf16* __restrict__ kv, const bf16* __restrict__ vT,
    float* __restrict__ pU, float* __restrict__ prs, float* __restrict__ avis, int write_avis)
{
    __shared__ bf16 as_[16 * 64];   // [s][t] rows 128B, XOR-swizzled
    __shared__ float rsw[4][16];
    int tid = threadIdx.x, lane = tid & 63, wid = tid >> 6;
    int b = blockIdx.x >> 4, chunk = blockIdx.x & 15;
    int t0 = chunk * TCH;
    int g = lane >> 4, s15 = lane & 15;
    const bf16* qb  = q_bf + (size_t)b * 16 * 768;
    const bf16* kb  = kv + (size_t)b * T_ * 1536;
    const bf16* vtb = vT + (size_t)b * 768 * T_;
    const f32x4 vzero = {0.f, 0.f, 0.f, 0.f};
    f32x4 uacc[12];
    #pragma unroll
    for (int i = 0; i < 12; ++i) uacc[i] = vzero;
    float rs_acc = 0.f;

    for (int w4 = 0; w4 < 4; ++w4) {
        int tb = t0 + w4 * 64;
        int trow = tb + wid * 16 + s15;
        f32x4 dacc = vzero;
        #pragma unroll
        for (int kk = 0; kk < 768; kk += 32) {
            s16x8 kf = *(const s16x8*)(kb + (size_t)trow * 1536 + kk + g * 8);
            s16x8 qf = *(const s16x8*)(qb + (size_t)s15 * 768 + kk + g * 8);
            dacc = __builtin_amdgcn_mfma_f32_16x16x32_bf16(kf, qf, dacc, 0, 0, 0);
        }
        float d0 = dacc[0] * SCALE, d1 = dacc[1] * SCALE,
              d2 = dacc[2] * SCALE, d3 = dacc[3] * SCALE;
        float m0 = d0, m1 = d1, m2 = d2, m3 = d3;
        #pragma unroll
        for (int off = 1; off < 16; off <<= 1) {
            m0 = fmaxf(m0, __shfl_xor(m0, off));
            m1 = fmaxf(m1, __shfl_xor(m1, off));
            m2 = fmaxf(m2, __shfl_xor(m2, off));
            m3 = fmaxf(m3, __shfl_xor(m3, off));
        }
        float e0 = expf(d0 - m0), e1 = expf(d1 - m1), e2 = expf(d2 - m2), e3 = expf(d3 - m3);
        float q0 = e0, q1 = e1, q2 = e2, q3 = e3;
        #pragma unroll
        for (int off = 1; off < 16; off <<= 1) {
            q0 += __shfl_xor(q0, off);
            q1 += __shfl_xor(q1, off);
            q2 += __shfl_xor(q2, off);
            q3 += __shfl_xor(q3, off);
        }
        float a0 = e0 / q0, a1 = e1 / q1, a2 = e2 / q2, a3 = e3 / q3;
        rs_acc += a0 + a1 + a2 + a3;
        u32 p01 = (u32)bfbits(a0) | ((u32)bfbits(a1) << 16);
        u32 p23 = (u32)bfbits(a2) | ((u32)bfbits(a3) << 16);
        uint2 pk; pk.x = p01; pk.y = p23;
        *(uint2*)((char*)as_ + s15 * 128 + ((wid * 32 + g * 8) ^ ((s15 & 7) << 4))) = pk;
        if (write_avis) {
            f32x4 w = {a0, a1, a2, a3};
            *(f32x4*)(avis + (size_t)(b * 16 + s15) * T_ + tb + wid * 16 + g * 4) = w;
        }
        __syncthreads();
        #pragma unroll
        for (int ks = 0; ks < 2; ++ks) {
            s16x8 af = *(const s16x8*)((const char*)as_ + s15 * 128 + ((ks * 64 + g * 16) ^ ((s15 & 7) << 4)));
            #pragma unroll
            for (int i = 0; i < 12; ++i) {
                int d = (wid * 12 + i) * 16 + s15;
                s16x8 vf = *(const s16x8*)(vtb + (size_t)d * T_ + tb + ks * 32 + g * 8);
                uacc[i] = __builtin_amdgcn_mfma_f32_16x16x32_bf16(vf, af, uacc[i], 0, 0, 0);
            }
        }
        __syncthreads();
    }
    float* pUb = pU + (size_t)(b * 16 + chunk) * 768 * 16;
    #pragma unroll
    for (int i = 0; i < 12; ++i) {
        int dbase = (wid * 12 + i) * 16 + g * 4;
        #pragma unroll
        for (int j = 0; j < 4; ++j)
            pUb[(size_t)(dbase + j) * 16 + s15] = uacc[i][j];
    }
    rs_acc += __shfl_xor(rs_acc, 16);
    rs_acc += __shfl_xor(rs_acc, 32);
    if (lane < 16) rsw[wid][s15] = rs_acc;
    __syncthreads();
    if (tid < 16)
        prs[(b * 16 + chunk) * 16 + tid] = rsw[0][tid] + rsw[1][tid] + rsw[2][tid] + rsw[3][tid];
}

// reduce partials: upd[b][s][d] = (sum_c pU + EPS*vsum[b][d]) / (sum_c prs + T*EPS)
__global__ void __launch_bounds__(256) attn_reduce_kernel(
    const float* __restrict__ pU, const float* __restrict__ prs,
    const float* __restrict__ vsum, bf16* __restrict__ upd)
{
    int idx = blockIdx.x * 256 + threadIdx.x;   // 16*16*768
    int d = idx % 768;
    int s = (idx / 768) & 15;
    int b = idx / (768 * 16);
    float su = 0.f;
    #pragma unroll
    for (int c = 0; c < 16; ++c) su += pU[((size_t)(b * 16 + c) * 768 + d) * 16 + s];
    float rs = 0.f;
    #pragma unroll
    for (int c = 0; c < 16; ++c) rs += prs[(b * 16 + c) * 16 + s];
    float val = (su + EPS * vsum[b * 768 + d]) / (rs + T_ * EPS);
    upd[idx] = __float2bfloat16(val);
}

// ---------------------------------------------------------------------------
// Fused GRU: gi = upd@Wih^T, gh = slots@Whh^T (6 output tiles), gates, write new slots.
// grid (16 batches, 12 col-tiles). No LDS: direct-global fragments.
__global__ void __launch_bounds__(256) fused_gru_kernel(
    const bf16* __restrict__ upd, const bf16* __restrict__ slots_bf,
    const bf16* __restrict__ Wih, const bf16* __restrict__ Whh,
    const float* __restrict__ bih, const float* __restrict__ bhh,
    const float* __restrict__ slots_f, float* __restrict__ slots_out)
{
    int tid = threadIdx.x, lane = tid & 63, wid = tid >> 6;
    int bx = blockIdx.x, c0 = blockIdx.y * 64;
    int g = lane >> 4, s15 = lane & 15;
    int cn = c0 + wid * 16 + s15;
    const f32x4 vz = {0.f, 0.f, 0.f, 0.f};
    f32x4 air = vz, aiz = vz, ain = vz, ahr = vz, ahz = vz, ahn = vz;
    const bf16* au_b = upd + (size_t)(bx * 16 + s15) * 768;
    const bf16* ah_b = slots_bf + (size_t)(bx * 16 + s15) * 768;
    const bf16* wr_ = Wih + (size_t)cn * 768;
    const bf16* wz_ = Wih + (size_t)(768 + cn) * 768;
    const bf16* wn_ = Wih + (size_t)(1536 + cn) * 768;
    const bf16* vr_ = Whh + (size_t)cn * 768;
    const bf16* vz_ = Whh + (size_t)(768 + cn) * 768;
    const bf16* vn_ = Whh + (size_t)(1536 + cn) * 768;
    for (int kk = 0; kk < 768; kk += 32) {
        int ko = kk + g * 8;
        s16x8 au = *(const s16x8*)(au_b + ko);
        s16x8 ah = *(const s16x8*)(ah_b + ko);
        air = __builtin_amdgcn_mfma_f32_16x16x32_bf16(au, *(const s16x8*)(wr_ + ko), air, 0, 0, 0);
        aiz = __builtin_amdgcn_mfma_f32_16x16x32_bf16(au, *(const s16x8*)(wz_ + ko), aiz, 0, 0, 0);
        ain = __builtin_amdgcn_mfma_f32_16x16x32_bf16(au, *(const s16x8*)(wn_ + ko), ain, 0, 0, 0);
        ahr = __builtin_amdgcn_mfma_f32_16x16x32_bf16(ah, *(const s16x8*)(vr_ + ko), ahr, 0, 0, 0);
        ahz = __builtin_amdgcn_mfma_f32_16x16x32_bf16(ah, *(const s16x8*)(vz_ + ko), ahz, 0, 0, 0);
        ahn = __builtin_amdgcn_mfma_f32_16x16x32_bf16(ah, *(const s16x8*)(vn_ + ko), ahn, 0, 0, 0);
    }
    float bir = bih[cn], biz = bih[768 + cn], bin_ = bih[1536 + cn];
    float bhr = bhh[cn], bhz = bhh[768 + cn], bhn = bhh[1536 + cn];
    #pragma unroll
    for (int j = 0; j < 4; ++j) {
        int m = bx * 16 + g * 4 + j;
        float ir = air[j] + bir, iz = aiz[j] + biz, inn = ain[j] + bin_;
        float hr = ahr[j] + bhr, hz = ahz[j] + bhz, hn = ahn[j] + bhn;
        float r = 1.f / (1.f + expf(-(ir + hr)));
        float z = 1.f / (1.f + expf(-(iz + hz)));
        float n = tanhf(inn + r * hn);
        float h = slots_f[(size_t)m * 768 + cn];
        slots_out[(size_t)m * 768 + cn] = (1.f - z) * n + z * h;
    }
}

// ---------------------------------------------------------------------------
// MLP out: slotsA = slotsB + h1@W2^T + b2. Direct-global fragments, no LDS.
// grid (16, 12).
__global__ void __launch_bounds__(256) mlp_out_kernel(
    const bf16* __restrict__ h1, const bf16* __restrict__ W2,
    const float* __restrict__ b2, const float* __restrict__ slots_in,
    float* __restrict__ slots_f, bf16* __restrict__ slots_b)
{
    int tid = threadIdx.x, lane = tid & 63, wid = tid >> 6;
    int bx = blockIdx.x, c0 = blockIdx.y * 64;
    int g = lane >> 4, s15 = lane & 15;
    int cn = c0 + wid * 16 + s15;
    const bf16* a_b = h1 + (size_t)(bx * 16 + s15) * 3072;
    const bf16* w_b = W2 + (size_t)cn * 3072;
    f32x4 acc = {0.f, 0.f, 0.f, 0.f};
    for (int kk = 0; kk < 3072; kk += 32) {
        s16x8 af = *(const s16x8*)(a_b + kk + g * 8);
        s16x8 bf_ = *(const s16x8*)(w_b + kk + g * 8);
        acc = __builtin_amdgcn_mfma_f32_16x16x32_bf16(af, bf_, acc, 0, 0, 0);
    }
    float bv = b2[cn];
    #pragma unroll
    for (int j = 0; j < 4; ++j) {
        int m = bx * 16 + g * 4 + j;
        float val = acc[j] + bv + slots_in[(size_t)m * 768 + cn];
        slots_f[(size_t)m * 768 + cn] = val;
        slots_b[(size_t)m * 768 + cn] = __float2bfloat16(val);
    }
}

// ---------------------------------------------------------------------------
// Clustering epilogue
__global__ void __launch_bounds__(256) cluster_kernel(
    const float* __restrict__ slots, float* __restrict__ out_slots,
    float* __restrict__ out_mask, float* __restrict__ cm_g)
{
    int b = blockIdx.x;
    __shared__ float s[16][768];
    __shared__ float inv[16];
    __shared__ float adj[16][16], tmp[16][16], cw[16][16];
    __shared__ int reset_s;
    const float* sb = slots + (size_t)b * 16 * 768;
    for (int i = threadIdx.x; i < 16 * 768; i += 256) s[i / 768][i % 768] = sb[i];
    __syncthreads();
    if (threadIdx.x < 16) {
        float q = 0.f;
        for (int d = 0; d < 768; ++d) q += s[threadIdx.x][d] * s[threadIdx.x][d];
        inv[threadIdx.x] = 1.f / fmaxf(sqrtf(q), 1e-12f);
    }
    __syncthreads();
    int n = threadIdx.x >> 4, m = threadIdx.x & 15;
    float dot = 0.f;
    for (int d = 0; d < 768; ++d) dot += s[n][d] * s[m][d];
    dot *= inv[n] * inv[m];
    adj[n][m] = ((1.f - dot) < 0.5f) ? 1.f : 0.f;
    __syncthreads();
    #pragma unroll
    for (int it = 0; it < 4; ++it) {
        float t = 0.f;
        #pragma unroll
        for (int j = 0; j < 16; ++j) t += adj[n][j] * adj[j][m];
        tmp[n][m] = fminf(t, 1.f);
        __syncthreads();
        adj[n][m] = tmp[n][m];
        __syncthreads();
    }
    if (threadIdx.x < 16) {
        int mm = threadIdx.x;
        float run = 0.f;
        for (int nn = 0; nn < 16; ++nn) {
            run += adj[nn][mm];
            tmp[nn][mm] = adj[nn][mm] * ((run <= 1.f) ? 1.f : 0.f);
        }
    }
    __syncthreads();
    if (threadIdx.x == 0) {
        int cnt = 0;
        for (int nn = 0; nn < 16; ++nn) {
            bool any = false;
            for (int j = 0; j < 16; ++j) any = any || (tmp[nn][j] > 0.f);
            cnt += any ? 1 : 0;
        }
        reset_s = (cnt < 3) ? 1 : 0;
    }
    __syncthreads();
    if (reset_s) tmp[n][m] = (n == m) ? 1.f : 0.f;
    __syncthreads();
    if (threadIdx.x < 16) {
        float rs = 0.f;
        for (int j = 0; j < 16; ++j) rs += tmp[threadIdx.x][j];
        rs = fmaxf(rs, 1.f);
        for (int j = 0; j < 16; ++j) cw[threadIdx.x][j] = tmp[threadIdx.x][j] / rs;
        bool any = false;
        for (int j = 0; j < 16; ++j) any = any || (tmp[threadIdx.x][j] > 0.f);
        out_mask[b * 16 + threadIdx.x] = any ? 1.f : 0.f;
    }
    cm_g[b * 256 + threadIdx.x] = tmp[n][m];
    __syncthreads();
    for (int i = threadIdx.x; i < 16 * 768; i += 256) {
        int nn = i / 768, d = i - nn * 768;
        float acc = 0.f;
        #pragma unroll
        for (int j = 0; j < 16; ++j) acc += cw[nn][j] * s[j][d];
        out_slots[(size_t)b * 16 * 768 + i] = acc;
    }
}

__global__ void __launch_bounds__(256) cattn_kernel(
    const float* __restrict__ av, const float* __restrict__ cm_g, float* __restrict__ out_attn)
{
    int b = blockIdx.y;
    int t = blockIdx.x * 256 + threadIdx.x;
    __shared__ float cm[16][16];
    cm[threadIdx.x >> 4][threadIdx.x & 15] = cm_g[b * 256 + threadIdx.x];
    __syncthreads();
    float avv[16];
    #pragma unroll
    for (int j = 0; j < 16; ++j) avv[j] = av[((size_t)b * 16 + j) * T_ + t];
    #pragma unroll
    for (int i = 0; i < 16; ++i) {
        float acc = 0.f;
        #pragma unroll
        for (int j = 0; j < 16; ++j) acc += cm[i][j] * avv[j];
        out_attn[((size_t)b * T_ + t) * 16 + i] = acc;
    }
}

// ---------------------------------------------------------------------------
extern "C" void kernel_launch(void* const* d_in, const int* in_sizes, int n_in,
                              void* d_out, int out_size, void* d_ws, size_t ws_size,
                              hipStream_t stream)
{
    const float* x    = (const float*)d_in[0];
    const float* si   = (const float*)d_in[3];
    const float* Wk   = (const float*)d_in[4];
    const float* Wv   = (const float*)d_in[5];
    const float* Wq   = (const float*)d_in[6];
    const float* gwih = (const float*)d_in[7];
    const float* gwhh = (const float*)d_in[8];
    const float* gbih = (const float*)d_in[9];
    const float* gbhh = (const float*)d_in[10];
    const float* w1   = (const float*)d_in[11];
    const float* b1   = (const float*)d_in[12];
    const float* w2   = (const float*)d_in[13];
    const float* b2   = (const float*)d_in[14];
    const float* ling = (const float*)d_in[15];
    const float* linb = (const float*)d_in[16];
    const float* lsg  = (const float*)d_in[17];
    const float* lsb  = (const float*)d_in[18];
    const float* lfg  = (const float*)d_in[19];
    const float* lfb  = (const float*)d_in[20];

    char* w = (char*)d_ws;
    size_t off = 0;
    auto alloc = [&](size_t bytes) { void* p = w + off; off += (bytes + 255) & ~(size_t)255; return p; };
    bf16* xn_vt  = (bf16*)alloc((size_t)B_ * T_ * D_ * 2);       // xn, later vT
    bf16* kv     = (bf16*)alloc((size_t)B_ * T_ * 1536 * 2);     // [k | v] cols
    float* avis  = (float*)alloc((size_t)B_ * NS * T_ * 4);
    float* pU    = (float*)alloc((size_t)B_ * NCHUNK * S_ * NS * 4);
    float* prs   = (float*)alloc((size_t)B_ * NCHUNK * NS * 4);
    float* vsum  = (float*)alloc((size_t)B_ * S_ * 4);
    float* slotsA = (float*)alloc((size_t)B_ * NS * S_ * 4);
    bf16* slotsA_bf = (bf16*)alloc((size_t)B_ * NS * S_ * 2);
    float* slotsB = (float*)alloc((size_t)B_ * NS * S_ * 4);
    bf16* q_bf   = (bf16*)alloc((size_t)B_ * NS * S_ * 2);
    bf16* upd_bf = (bf16*)alloc((size_t)B_ * NS * S_ * 2);
    bf16* h1_bf  = (bf16*)alloc((size_t)B_ * NS * 4 * S_ * 2);
    bf16* wq_bf  = (bf16*)alloc((size_t)S_ * S_ * 2);
    bf16* wkv_bf = (bf16*)alloc((size_t)1536 * D_ * 2);
    bf16* gwih_bf = (bf16*)alloc((size_t)3 * S_ * S_ * 2);
    bf16* gwhh_bf = (bf16*)alloc((size_t)3 * S_ * S_ * 2);
    bf16* w1_bf  = (bf16*)alloc((size_t)4 * S_ * S_ * 2);
    bf16* w2_bf  = (bf16*)alloc((size_t)S_ * 4 * S_ * 2);
    float* cm_g  = (float*)alloc((size_t)B_ * 256 * 4);

    float* out_slots = (float*)d_out;
    float* out_attn  = out_slots + (size_t)B_ * NS * S_;
    float* out_mask  = out_attn + (size_t)B_ * T_ * NS;

    // weight conversions (one launch)
    cvt_all_kernel<<<39168, 256, 0, stream>>>(Wq, Wk, Wv, gwih, gwhh, w1, w2,
                                              wq_bf, wkv_bf, gwih_bf, gwhh_bf, w1_bf, w2_bf);

    // LN(x) -> xn (bf16)
    ln768_kernel<<<B_ * T_, 256, 0, stream>>>(x, ling, linb, xn_vt);

    // fused k|v projection: [65536 x 1536]
    {
        dim3 g(1536 / 128, B_ * T_ / 128);
        gemm128_kernel<<<g, 256, 0, stream>>>(xn_vt, wkv_bf, kv, B_ * T_, 1536, D_);
    }

    // vT (reuse xn buffer) + vsum
    hipMemsetAsync(vsum, 0, (size_t)B_ * S_ * 4, stream);
    {
        dim3 g(T_ / 32, S_ / 32, B_);
        transpose_vsum_kernel<<<g, 256, 0, stream>>>(kv, xn_vt, vsum);
    }
    bf16* vT = xn_vt;

    init_slots_kernel<<<(B_ * NS * S_) / 256, 256, 0, stream>>>(si, slotsA, slotsA_bf);

    for (int it = 0; it < NIT; ++it) {
        // q = LN(slotsA) @ Wq^T
        {
            dim3 g(16, 12);
            ln_gemm_kernel<<<g, 256, 0, stream>>>(slotsA, lsg, lsb, wq_bf, nullptr,
                                                  q_bf, 768, 0);
        }
        fused_attn_kernel<<<B_ * NCHUNK, 256, 0, stream>>>(q_bf, kv, vT, pU, prs, avis,
                                                           (it == NIT - 1) ? 1 : 0);
        attn_reduce_kernel<<<(B_ * NS * S_) / 256, 256, 0, stream>>>(pU, prs, vsum, upd_bf);
        {
            dim3 g(16, 12);
            fused_gru_kernel<<<g, 256, 0, stream>>>(upd_bf, slotsA_bf, gwih_bf, gwhh_bf,
                                                    gbih, gbhh, slotsA, slotsB);
        }
        // h1 = relu(LN(slotsB) @ w1^T + b1)
        {
            dim3 g(16, 48);
            ln_gemm_kernel<<<g, 256, 0, stream>>>(slotsB, lfg, lfb, w1_bf, b1,
                                                  h1_bf, 3072, 1);
        }
        // slotsA = slotsB + h1 @ w2^T + b2
        {
            dim3 g(16, 12);
            mlp_out_kernel<<<g, 256, 0, stream>>>(h1_bf, w2_bf, b2, slotsB,
                                                  slotsA, slotsA_bf);
        }
    }

    cluster_kernel<<<B_, 256, 0, stream>>>(slotsA, out_slots, out_mask, cm_g);
    {
        dim3 g(T_ / 256, B_);
        cattn_kernel<<<g, 256, 0, stream>>>(avis, cm_g, out_attn);
    }
}

// Round 4
// 1840.519 us; speedup vs baseline: 1.1372x; 1.1372x over previous
//
#include <hip/hip_runtime.h>
#include <hip/hip_bf16.h>

typedef __hip_bfloat16 bf16;
typedef __attribute__((ext_vector_type(4))) float f32x4;
typedef __attribute__((ext_vector_type(8))) short s16x8;
typedef unsigned int u32;
typedef unsigned short u16;

#define B_ 16
#define T_ 4096
#define D_ 768
#define S_ 768
#define NS 16
#define NIT 9
#define NCHUNK 16
#define TCH 256
#define EPS 1e-8f
#define SCALE 0.036084391824351615f  /* 768^-0.5 */

__device__ __forceinline__ void gld16(const void* g, void* l) {
    __builtin_amdgcn_global_load_lds((const __attribute__((address_space(1))) u32*)g,
                                     (__attribute__((address_space(3))) u32*)l, 16, 0, 0);
}

__device__ __forceinline__ u16 bfbits(float x) {
    bf16 h = __float2bfloat16(x);
    return *reinterpret_cast<u16*>(&h);
}

// ---------------------------------------------------------------------------
// All weight conversions in one launch. wkv = [Wk rows; Wv rows] (1536 x 768).
__global__ void __launch_bounds__(256) cvt_all_kernel(
    const float* __restrict__ wq, const float* __restrict__ wk, const float* __restrict__ wv,
    const float* __restrict__ gwih, const float* __restrict__ gwhh,
    const float* __restrict__ w1, const float* __restrict__ w2,
    bf16* __restrict__ wq_b, bf16* __restrict__ wkv_b,
    bf16* __restrict__ gwih_b, bf16* __restrict__ gwhh_b,
    bf16* __restrict__ w1_b, bf16* __restrict__ w2_b)
{
    int i = blockIdx.x * 256 + threadIdx.x;
    const int NW = 589824, NG = 1769472, NM = 2359296;
    if (i < NW) { wq_b[i] = __float2bfloat16(wq[i]); return; }
    i -= NW;
    if (i < NW) { wkv_b[i] = __float2bfloat16(wk[i]); return; }
    i -= NW;
    if (i < NW) { wkv_b[NW + i] = __float2bfloat16(wv[i]); return; }
    i -= NW;
    if (i < NG) { gwih_b[i] = __float2bfloat16(gwih[i]); return; }
    i -= NG;
    if (i < NG) { gwhh_b[i] = __float2bfloat16(gwhh[i]); return; }
    i -= NG;
    if (i < NM) { w1_b[i] = __float2bfloat16(w1[i]); return; }
    i -= NM;
    w2_b[i] = __float2bfloat16(w2[i]);
}

// ---------------------------------------------------------------------------
// LayerNorm over rows of width 768, fp32 in -> bf16 out. One 256-thread block per row.
__global__ void __launch_bounds__(256) ln768_kernel(
    const float* __restrict__ x, const float* __restrict__ g,
    const float* __restrict__ bta, bf16* __restrict__ out)
{
    int row = blockIdx.x;
    int tid = threadIdx.x;
    const float* xr = x + (size_t)row * 768;
    float v0 = xr[tid], v1 = xr[tid + 256], v2 = xr[tid + 512];
    float s = v0 + v1 + v2;
    int lane = tid & 63, wid = tid >> 6;
    #pragma unroll
    for (int off = 32; off; off >>= 1) s += __shfl_down(s, off);
    __shared__ float red[4];
    __shared__ float sh_mu, sh_rs;
    if (lane == 0) red[wid] = s;
    __syncthreads();
    if (tid == 0) sh_mu = (red[0] + red[1] + red[2] + red[3]) * (1.f / 768.f);
    __syncthreads();
    float mu = sh_mu;
    float d0 = v0 - mu, d1 = v1 - mu, d2 = v2 - mu;
    float q = d0 * d0 + d1 * d1 + d2 * d2;
    #pragma unroll
    for (int off = 32; off; off >>= 1) q += __shfl_down(q, off);
    if (lane == 0) red[wid] = q;
    __syncthreads();
    if (tid == 0) sh_rs = rsqrtf((red[0] + red[1] + red[2] + red[3]) * (1.f / 768.f) + 1e-5f);
    __syncthreads();
    float rs = sh_rs;
    bf16* orow = out + (size_t)row * 768;
    orow[tid]       = __float2bfloat16(d0 * rs * g[tid]       + bta[tid]);
    orow[tid + 256] = __float2bfloat16(d1 * rs * g[tid + 256] + bta[tid + 256]);
    orow[tid + 512] = __float2bfloat16(d2 * rs * g[tid + 512] + bta[tid + 512]);
}

// ---------------------------------------------------------------------------
// 128x128 tiled NT GEMM, BK=64, single-buffered global_load_lds, XCD-swizzled
// 1D grid: each XCD owns a contiguous M-range, N-fast within.
__global__ void __launch_bounds__(256) gemm128_kernel(
    const bf16* __restrict__ A, const bf16* __restrict__ Bm, bf16* __restrict__ Cb,
    int M, int N, int K, int nTilesN)
{
    __shared__ bf16 As[128 * 64];
    __shared__ bf16 Bs[128 * 64];
    int tid = threadIdx.x, lane = tid & 63, wid = tid >> 6;
    int per_xcd = gridDim.x >> 3;
    int xcd = blockIdx.x & 7;
    int idx = blockIdx.x >> 3;
    int mt = xcd * (per_xcd / nTilesN) + idx / nTilesN;
    int nt = idx % nTilesN;
    int bm0 = mt * 128, bn0 = nt * 128;
    int wr = wid >> 1, wc = wid & 1;
    int g = lane >> 4, r15 = lane & 15;
    const f32x4 vzero = {0.f, 0.f, 0.f, 0.f};
    f32x4 acc[4][4];
    #pragma unroll
    for (int m = 0; m < 4; ++m)
        #pragma unroll
        for (int n = 0; n < 4; ++n) acc[m][n] = vzero;

    for (int kt = 0; kt < K; kt += 64) {
        __syncthreads();
        #pragma unroll
        for (int i = 0; i < 4; ++i) {
            int sa = wid * 64 + i * 256;
            int o = (sa + lane) * 16;
            int r = o >> 7, cb = o & 127;
            int cbs = cb ^ ((r & 7) << 4);
            gld16(A + (size_t)(bm0 + r) * K + kt + (cbs >> 1), (char*)As + (size_t)sa * 16);
        }
        #pragma unroll
        for (int i = 0; i < 4; ++i) {
            int sa = wid * 64 + i * 256;
            int o = (sa + lane) * 16;
            int r = o >> 7, cb = o & 127;
            int cbs = cb ^ ((r & 7) << 4);
            gld16(Bm + (size_t)(bn0 + r) * K + kt + (cbs >> 1), (char*)Bs + (size_t)sa * 16);
        }
        asm volatile("s_waitcnt vmcnt(0)" ::: "memory");
        __syncthreads();
        #pragma unroll
        for (int kk = 0; kk < 64; kk += 32) {
            s16x8 af[4], bfr[4];
            #pragma unroll
            for (int m = 0; m < 4; ++m) {
                int r = wr * 64 + m * 16 + r15;
                int p = r * 128 + ((kk * 2 + g * 16) ^ ((r & 7) << 4));
                af[m] = *(const s16x8*)((const char*)As + p);
            }
            #pragma unroll
            for (int n = 0; n < 4; ++n) {
                int r = wc * 64 + n * 16 + r15;
                int p = r * 128 + ((kk * 2 + g * 16) ^ ((r & 7) << 4));
                bfr[n] = *(const s16x8*)((const char*)Bs + p);
            }
            #pragma unroll
            for (int m = 0; m < 4; ++m)
                #pragma unroll
                for (int n = 0; n < 4; ++n)
                    acc[m][n] = __builtin_amdgcn_mfma_f32_16x16x32_bf16(af[m], bfr[n], acc[m][n], 0, 0, 0);
        }
    }
    #pragma unroll
    for (int m = 0; m < 4; ++m) {
        int cm = bm0 + wr * 64 + m * 16 + g * 4;
        #pragma unroll
        for (int n = 0; n < 4; ++n) {
            int cn = bn0 + wc * 64 + n * 16 + r15;
            #pragma unroll
            for (int j = 0; j < 4; ++j)
                Cb[(size_t)(cm + j) * N + cn] = __float2bfloat16(acc[m][n][j]);
        }
    }
}

// ---------------------------------------------------------------------------
// Transpose v-part of kv [B,T,1536(cols 768..)] -> vT [B,768,T], plus vsum atomic.
__global__ void __launch_bounds__(256) transpose_vsum_kernel(
    const bf16* __restrict__ kv, bf16* __restrict__ vt, float* __restrict__ vsum)
{
    __shared__ bf16 tile[32][33];
    int b = blockIdx.z;
    int t0 = blockIdx.x * 32, d0 = blockIdx.y * 32;
    int tx = threadIdx.x & 31, ty = threadIdx.x >> 5;
    const bf16* vb = kv + (size_t)b * T_ * 1536 + 768;
    bf16* vtb = vt + (size_t)b * S_ * T_;
    #pragma unroll
    for (int r = ty; r < 32; r += 8)
        tile[r][tx] = vb[(size_t)(t0 + r) * 1536 + d0 + tx];
    __syncthreads();
    #pragma unroll
    for (int r = ty; r < 32; r += 8)
        vtb[(size_t)(d0 + r) * T_ + t0 + tx] = tile[tx][r];
    if (threadIdx.x < 32) {
        float s = 0.f;
        #pragma unroll
        for (int r = 0; r < 32; ++r) s += __bfloat162float(tile[r][threadIdx.x]);
        atomicAdd(vsum + b * 768 + d0 + threadIdx.x, s);
    }
}

// ---------------------------------------------------------------------------
__global__ void init_slots_kernel(const float* __restrict__ si,
                                  float* __restrict__ slots, bf16* __restrict__ slots_bf)
{
    int idx = blockIdx.x * 256 + threadIdx.x;  // 256*768
    float v = si[idx % (NS * S_)];
    slots[idx] = v;
    slots_bf[idx] = __float2bfloat16(v);
}

// ---------------------------------------------------------------------------
// Fused LN(rows of 16) + NT GEMM: out[m, cn] = act(LN(x)[m,:] @ W[cn,:] + bias[cn])
// grid (M/16, N/64). W: [N][768] bf16. out bf16 [M][N].
__global__ void __launch_bounds__(256) ln_gemm_kernel(
    const float* __restrict__ xin, const float* __restrict__ gam, const float* __restrict__ bet,
    const bf16* __restrict__ W, const float* __restrict__ bias,
    bf16* __restrict__ out, int N, int relu)
{
    __shared__ bf16 As[16 * 768];  // rows 1536B, XOR-swizzled
    int tid = threadIdx.x;
    int bx = blockIdx.x, bn0 = blockIdx.y * 64;
    int row = tid >> 4, li = tid & 15;
    const float* xr = xin + (size_t)(bx * 16 + row) * 768;
    float vals[48];
    float s = 0.f;
    #pragma unroll
    for (int i = 0; i < 48; ++i) { vals[i] = xr[li + i * 16]; s += vals[i]; }
    #pragma unroll
    for (int m = 1; m < 16; m <<= 1) s += __shfl_xor(s, m);
    float mu = s * (1.f / 768.f);
    float q = 0.f;
    #pragma unroll
    for (int i = 0; i < 48; ++i) { float d = vals[i] - mu; q += d * d; }
    #pragma unroll
    for (int m = 1; m < 16; m <<= 1) q += __shfl_xor(q, m);
    float rs = rsqrtf(q * (1.f / 768.f) + 1e-5f);
    #pragma unroll
    for (int i = 0; i < 48; ++i) {
        int c = li + i * 16;
        float v = (vals[i] - mu) * rs * gam[c] + bet[c];
        *(u16*)((char*)As + row * 1536 + ((c * 2) ^ ((row & 7) << 4))) = bfbits(v);
    }
    __syncthreads();
    int lane = tid & 63, wid = tid >> 6;
    int g = lane >> 4, s15 = lane & 15;
    int cn = bn0 + wid * 16 + s15;
    f32x4 acc = {0.f, 0.f, 0.f, 0.f};
    for (int kk = 0; kk < 768; kk += 32) {
        s16x8 af = *(const s16x8*)((const char*)As + s15 * 1536 + ((kk * 2 + g * 16) ^ ((s15 & 7) << 4)));
        s16x8 bf_ = *(const s16x8*)(W + (size_t)cn * 768 + kk + g * 8);
        acc = __builtin_amdgcn_mfma_f32_16x16x32_bf16(af, bf_, acc, 0, 0, 0);
    }
    float bv = bias ? bias[cn] : 0.f;
    #pragma unroll
    for (int j = 0; j < 4; ++j) {
        float val = acc[j] + bv;
        if (relu) val = fmaxf(val, 0.f);
        out[(size_t)(bx * 16 + g * 4 + j) * N + cn] = __float2bfloat16(val);
    }
}

// ---------------------------------------------------------------------------
// Fused attention step (LDS-staged): per (batch, 256-t chunk):
//   dotsT = k_tile @ q^T * SCALE ; softmax over slots (local per t);
//   partial U^T[d][s] += vT_tile @ a^T ; partial rowsum[s] += sum_t a.
// k comes from fused kv (row stride 1536, cols 0..767).
__global__ void __launch_bounds__(256) fused_attn_kernel(
    const bf16* __restrict__ q_bf, const bf16* __restrict__ kv, const bf16* __restrict__ vT,
    float* __restrict__ pU, float* __restrict__ prs, float* __restrict__ avis, int write_avis)
{
    __shared__ bf16 qs[16 * 768];    // [16][1536B] swizzled (24KB)
    __shared__ bf16 ks[32 * 768];    // [32][1536B] swizzled (48KB)
    __shared__ bf16 vs[768 * 32];    // [768][64B]  swizzled (48KB)
    __shared__ bf16 as_[16 * 32];    // [16][64B]   swizzled (1KB)
    __shared__ float rsw[2][16];
    int tid = threadIdx.x, lane = tid & 63, wid = tid >> 6;
    int b = blockIdx.x >> 4, chunk = blockIdx.x & 15;
    int t0 = chunk * TCH;
    int g = lane >> 4, s15 = lane & 15;
    const bf16* qb  = q_bf + (size_t)b * 16 * 768;
    const bf16* kb  = kv + (size_t)b * T_ * 1536;
    const bf16* vtb = vT + (size_t)b * 768 * T_;

    // stage q once (1536 segs of 16B)
    #pragma unroll
    for (int i = 0; i < 6; ++i) {
        int s0 = i * 256 + wid * 64;
        int o = (s0 + lane) * 16;
        int r = o / 1536, cb = o % 1536;
        int cbs = cb ^ ((r & 7) << 4);
        gld16(qb + (size_t)r * 768 + (cbs >> 1), (char*)qs + (size_t)s0 * 16);
    }

    const f32x4 vzero = {0.f, 0.f, 0.f, 0.f};
    f32x4 uacc[12];
    #pragma unroll
    for (int i = 0; i < 12; ++i) uacc[i] = vzero;
    float rs_acc = 0.f;

    for (int ts = 0; ts < TCH / 32; ++ts) {
        int tb = t0 + ts * 32;
        __syncthreads();   // previous step's LDS reads done
        #pragma unroll
        for (int i = 0; i < 12; ++i) {   // k-tile: [32][1536B]
            int s0 = i * 256 + wid * 64;
            int o = (s0 + lane) * 16;
            int r = o / 1536, cb = o % 1536;
            int cbs = cb ^ ((r & 7) << 4);
            gld16(kb + (size_t)(tb + r) * 1536 + (cbs >> 1), (char*)ks + (size_t)s0 * 16);
        }
        #pragma unroll
        for (int i = 0; i < 12; ++i) {   // vT-tile: [768][64B]
            int s0 = i * 256 + wid * 64;
            int o = (s0 + lane) * 16;
            int d = o >> 6, cb = o & 63;
            int cbs = cb ^ ((d & 3) << 4);
            gld16(vtb + (size_t)d * T_ + tb + (cbs >> 1), (char*)vs + (size_t)s0 * 16);
        }
        asm volatile("s_waitcnt vmcnt(0)" ::: "memory");
        __syncthreads();

        if (wid < 2) {
            f32x4 dacc = vzero;
            #pragma unroll
            for (int kk = 0; kk < 768; kk += 32) {
                int rk = wid * 16 + s15;
                int pk = rk * 1536 + ((kk * 2 + g * 16) ^ ((rk & 7) << 4));
                s16x8 kf = *(const s16x8*)((const char*)ks + pk);
                int pq = s15 * 1536 + ((kk * 2 + g * 16) ^ ((s15 & 7) << 4));
                s16x8 qf = *(const s16x8*)((const char*)qs + pq);
                dacc = __builtin_amdgcn_mfma_f32_16x16x32_bf16(kf, qf, dacc, 0, 0, 0);
            }
            float d0 = dacc[0] * SCALE, d1 = dacc[1] * SCALE,
                  d2 = dacc[2] * SCALE, d3 = dacc[3] * SCALE;
            float m0 = d0, m1 = d1, m2 = d2, m3 = d3;
            #pragma unroll
            for (int off = 1; off < 16; off <<= 1) {
                m0 = fmaxf(m0, __shfl_xor(m0, off));
                m1 = fmaxf(m1, __shfl_xor(m1, off));
                m2 = fmaxf(m2, __shfl_xor(m2, off));
                m3 = fmaxf(m3, __shfl_xor(m3, off));
            }
            float e0 = expf(d0 - m0), e1 = expf(d1 - m1), e2 = expf(d2 - m2), e3 = expf(d3 - m3);
            float q0 = e0, q1 = e1, q2 = e2, q3 = e3;
            #pragma unroll
            for (int off = 1; off < 16; off <<= 1) {
                q0 += __shfl_xor(q0, off);
                q1 += __shfl_xor(q1, off);
                q2 += __shfl_xor(q2, off);
                q3 += __shfl_xor(q3, off);
            }
            float a0 = e0 / q0, a1 = e1 / q1, a2 = e2 / q2, a3 = e3 / q3;
            rs_acc += a0 + a1 + a2 + a3;
            int tl = wid * 16 + g * 4;
            ushort2 p0, p1;
            p0.x = bfbits(a0); p0.y = bfbits(a1);
            p1.x = bfbits(a2); p1.y = bfbits(a3);
            int sw = (s15 & 3) << 4;
            *(ushort2*)((char*)as_ + s15 * 64 + ((tl * 2) ^ sw))       = p0;
            *(ushort2*)((char*)as_ + s15 * 64 + (((tl + 2) * 2) ^ sw)) = p1;
            if (write_avis) {
                f32x4 w = {a0, a1, a2, a3};
                *(f32x4*)(avis + (size_t)(b * 16 + s15) * T_ + tb + tl) = w;
            }
        }
        __syncthreads();
        // updates: all 4 waves, 12 d-tiles each
        {
            int pa = s15 * 64 + ((g * 16) ^ ((s15 & 3) << 4));
            s16x8 afr = *(const s16x8*)((const char*)as_ + pa);
            #pragma unroll
            for (int i = 0; i < 12; ++i) {
                int d = (wid * 12 + i) * 16 + s15;
                int pv = d * 64 + ((g * 16) ^ ((d & 3) << 4));
                s16x8 vf = *(const s16x8*)((const char*)vs + pv);
                uacc[i] = __builtin_amdgcn_mfma_f32_16x16x32_bf16(vf, afr, uacc[i], 0, 0, 0);
            }
        }
    }
    // write partial U^T: layout [b][chunk][d][s]
    float* pUb = pU + (size_t)(b * 16 + chunk) * 768 * 16;
    #pragma unroll
    for (int i = 0; i < 12; ++i) {
        int dbase = (wid * 12 + i) * 16 + g * 4;
        #pragma unroll
        for (int j = 0; j < 4; ++j)
            pUb[(size_t)(dbase + j) * 16 + s15] = uacc[i][j];
    }
    rs_acc += __shfl_xor(rs_acc, 16);
    rs_acc += __shfl_xor(rs_acc, 32);
    if (wid < 2 && lane < 16) rsw[wid][s15] = rs_acc;
    __syncthreads();
    if (tid < 16) prs[(b * 16 + chunk) * 16 + tid] = rsw[0][tid] + rsw[1][tid];
}

// reduce partials: upd[b][s][d] = (sum_c pU + EPS*vsum[b][d]) / (sum_c prs + T*EPS)
__global__ void __launch_bounds__(256) attn_reduce_kernel(
    const float* __restrict__ pU, const float* __restrict__ prs,
    const float* __restrict__ vsum, bf16* __restrict__ upd)
{
    int idx = blockIdx.x * 256 + threadIdx.x;   // 16*16*768
    int d = idx % 768;
    int s = (idx / 768) & 15;
    int b = idx / (768 * 16);
    float su = 0.f;
    #pragma unroll
    for (int c = 0; c < 16; ++c) su += pU[((size_t)(b * 16 + c) * 768 + d) * 16 + s];
    float rs = 0.f;
    #pragma unroll
    for (int c = 0; c < 16; ++c) rs += prs[(b * 16 + c) * 16 + s];
    float val = (su + EPS * vsum[b * 768 + d]) / (rs + T_ * EPS);
    upd[idx] = __float2bfloat16(val);
}

// ---------------------------------------------------------------------------
// Fused GRU: gi = upd@Wih^T, gh = slots@Whh^T (6 output tiles), gates, write new slots.
// grid (16 batches, 12 col-tiles). No LDS: direct-global fragments.
__global__ void __launch_bounds__(256) fused_gru_kernel(
    const bf16* __restrict__ upd, const bf16* __restrict__ slots_bf,
    const bf16* __restrict__ Wih, const bf16* __restrict__ Whh,
    const float* __restrict__ bih, const float* __restrict__ bhh,
    const float* __restrict__ slots_f, float* __restrict__ slots_out)
{
    int tid = threadIdx.x, lane = tid & 63, wid = tid >> 6;
    int bx = blockIdx.x, c0 = blockIdx.y * 64;
    int g = lane >> 4, s15 = lane & 15;
    int cn = c0 + wid * 16 + s15;
    const f32x4 vz = {0.f, 0.f, 0.f, 0.f};
    f32x4 air = vz, aiz = vz, ain = vz, ahr = vz, ahz = vz, ahn = vz;
    const bf16* au_b = upd + (size_t)(bx * 16 + s15) * 768;
    const bf16* ah_b = slots_bf + (size_t)(bx * 16 + s15) * 768;
    const bf16* wr_ = Wih + (size_t)cn * 768;
    const bf16* wz_ = Wih + (size_t)(768 + cn) * 768;
    const bf16* wn_ = Wih + (size_t)(1536 + cn) * 768;
    const bf16* vr_ = Whh + (size_t)cn * 768;
    const bf16* vz_ = Whh + (size_t)(768 + cn) * 768;
    const bf16* vn_ = Whh + (size_t)(1536 + cn) * 768;
    for (int kk = 0; kk < 768; kk += 32) {
        int ko = kk + g * 8;
        s16x8 au = *(const s16x8*)(au_b + ko);
        s16x8 ah = *(const s16x8*)(ah_b + ko);
        air = __builtin_amdgcn_mfma_f32_16x16x32_bf16(au, *(const s16x8*)(wr_ + ko), air, 0, 0, 0);
        aiz = __builtin_amdgcn_mfma_f32_16x16x32_bf16(au, *(const s16x8*)(wz_ + ko), aiz, 0, 0, 0);
        ain = __builtin_amdgcn_mfma_f32_16x16x32_bf16(au, *(const s16x8*)(wn_ + ko), ain, 0, 0, 0);
        ahr = __builtin_amdgcn_mfma_f32_16x16x32_bf16(ah, *(const s16x8*)(vr_ + ko), ahr, 0, 0, 0);
        ahz = __builtin_amdgcn_mfma_f32_16x16x32_bf16(ah, *(const s16x8*)(vz_ + ko), ahz, 0, 0, 0);
        ahn = __builtin_amdgcn_mfma_f32_16x16x32_bf16(ah, *(const s16x8*)(vn_ + ko), ahn, 0, 0, 0);
    }
    float bir = bih[cn], biz = bih[768 + cn], bin_ = bih[1536 + cn];
    float bhr = bhh[cn], bhz = bhh[768 + cn], bhn = bhh[1536 + cn];
    #pragma unroll
    for (int j = 0; j < 4; ++j) {
        int m = bx * 16 + g * 4 + j;
        float ir = air[j] + bir, iz = aiz[j] + biz, inn = ain[j] + bin_;
        float hr = ahr[j] + bhr, hz = ahz[j] + bhz, hn = ahn[j] + bhn;
        float r = 1.f / (1.f + expf(-(ir + hr)));
        float z = 1.f / (1.f + expf(-(iz + hz)));
        float n = tanhf(inn + r * hn);
        float h = slots_f[(size_t)m * 768 + cn];
        slots_out[(size_t)m * 768 + cn] = (1.f - z) * n + z * h;
    }
}

// ---------------------------------------------------------------------------
// MLP out: slotsA = slotsB + h1@W2^T + b2. Direct-global fragments, no LDS.
// grid (16, 12).
__global__ void __launch_bounds__(256) mlp_out_kernel(
    const bf16* __restrict__ h1, const bf16* __restrict__ W2,
    const float* __restrict__ b2, const float* __restrict__ slots_in,
    float* __restrict__ slots_f, bf16* __restrict__ slots_b)
{
    int tid = threadIdx.x, lane = tid & 63, wid = tid >> 6;
    int bx = blockIdx.x, c0 = blockIdx.y * 64;
    int g = lane >> 4, s15 = lane & 15;
    int cn = c0 + wid * 16 + s15;
    const bf16* a_b = h1 + (size_t)(bx * 16 + s15) * 3072;
    const bf16* w_b = W2 + (size_t)cn * 3072;
    f32x4 acc = {0.f, 0.f, 0.f, 0.f};
    for (int kk = 0; kk < 3072; kk += 32) {
        s16x8 af = *(const s16x8*)(a_b + kk + g * 8);
        s16x8 bf_ = *(const s16x8*)(w_b + kk + g * 8);
        acc = __builtin_amdgcn_mfma_f32_16x16x32_bf16(af, bf_, acc, 0, 0, 0);
    }
    float bv = b2[cn];
    #pragma unroll
    for (int j = 0; j < 4; ++j) {
        int m = bx * 16 + g * 4 + j;
        float val = acc[j] + bv + slots_in[(size_t)m * 768 + cn];
        slots_f[(size_t)m * 768 + cn] = val;
        slots_b[(size_t)m * 768 + cn] = __float2bfloat16(val);
    }
}

// ---------------------------------------------------------------------------
// Clustering epilogue
__global__ void __launch_bounds__(256) cluster_kernel(
    const float* __restrict__ slots, float* __restrict__ out_slots,
    float* __restrict__ out_mask, float* __restrict__ cm_g)
{
    int b = blockIdx.x;
    __shared__ float s[16][768];
    __shared__ float inv[16];
    __shared__ float adj[16][16], tmp[16][16], cw[16][16];
    __shared__ int reset_s;
    const float* sb = slots + (size_t)b * 16 * 768;
    for (int i = threadIdx.x; i < 16 * 768; i += 256) s[i / 768][i % 768] = sb[i];
    __syncthreads();
    if (threadIdx.x < 16) {
        float q = 0.f;
        for (int d = 0; d < 768; ++d) q += s[threadIdx.x][d] * s[threadIdx.x][d];
        inv[threadIdx.x] = 1.f / fmaxf(sqrtf(q), 1e-12f);
    }
    __syncthreads();
    int n = threadIdx.x >> 4, m = threadIdx.x & 15;
    float dot = 0.f;
    for (int d = 0; d < 768; ++d) dot += s[n][d] * s[m][d];
    dot *= inv[n] * inv[m];
    adj[n][m] = ((1.f - dot) < 0.5f) ? 1.f : 0.f;
    __syncthreads();
    #pragma unroll
    for (int it = 0; it < 4; ++it) {
        float t = 0.f;
        #pragma unroll
        for (int j = 0; j < 16; ++j) t += adj[n][j] * adj[j][m];
        tmp[n][m] = fminf(t, 1.f);
        __syncthreads();
        adj[n][m] = tmp[n][m];
        __syncthreads();
    }
    if (threadIdx.x < 16) {
        int mm = threadIdx.x;
        float run = 0.f;
        for (int nn = 0; nn < 16; ++nn) {
            run += adj[nn][mm];
            tmp[nn][mm] = adj[nn][mm] * ((run <= 1.f) ? 1.f : 0.f);
        }
    }
    __syncthreads();
    if (threadIdx.x == 0) {
        int cnt = 0;
        for (int nn = 0; nn < 16; ++nn) {
            bool any = false;
            for (int j = 0; j < 16; ++j) any = any || (tmp[nn][j] > 0.f);
            cnt += any ? 1 : 0;
        }
        reset_s = (cnt < 3) ? 1 : 0;
    }
    __syncthreads();
    if (reset_s) tmp[n][m] = (n == m) ? 1.f : 0.f;
    __syncthreads();
    if (threadIdx.x < 16) {
        float rs = 0.f;
        for (int j = 0; j < 16; ++j) rs += tmp[threadIdx.x][j];
        rs = fmaxf(rs, 1.f);
        for (int j = 0; j < 16; ++j) cw[threadIdx.x][j] = tmp[threadIdx.x][j] / rs;
        bool any = false;
        for (int j = 0; j < 16; ++j) any = any || (tmp[threadIdx.x][j] > 0.f);
        out_mask[b * 16 + threadIdx.x] = any ? 1.f : 0.f;
    }
    cm_g[b * 256 + threadIdx.x] = tmp[n][m];
    __syncthreads();
    for (int i = threadIdx.x; i < 16 * 768; i += 256) {
        int nn = i / 768, d = i - nn * 768;
        float acc = 0.f;
        #pragma unroll
        for (int j = 0; j < 16; ++j) acc += cw[nn][j] * s[j][d];
        out_slots[(size_t)b * 16 * 768 + i] = acc;
    }
}

__global__ void __launch_bounds__(256) cattn_kernel(
    const float* __restrict__ av, const float* __restrict__ cm_g, float* __restrict__ out_attn)
{
    int b = blockIdx.y;
    int t = blockIdx.x * 256 + threadIdx.x;
    __shared__ float cm[16][16];
    cm[threadIdx.x >> 4][threadIdx.x & 15] = cm_g[b * 256 + threadIdx.x];
    __syncthreads();
    float avv[16];
    #pragma unroll
    for (int j = 0; j < 16; ++j) avv[j] = av[((size_t)b * 16 + j) * T_ + t];
    #pragma unroll
    for (int i = 0; i < 16; ++i) {
        float acc = 0.f;
        #pragma unroll
        for (int j = 0; j < 16; ++j) acc += cm[i][j] * avv[j];
        out_attn[((size_t)b * T_ + t) * 16 + i] = acc;
    }
}

// ---------------------------------------------------------------------------
extern "C" void kernel_launch(void* const* d_in, const int* in_sizes, int n_in,
                              void* d_out, int out_size, void* d_ws, size_t ws_size,
                              hipStream_t stream)
{
    const float* x    = (const float*)d_in[0];
    const float* si   = (const float*)d_in[3];
    const float* Wk   = (const float*)d_in[4];
    const float* Wv   = (const float*)d_in[5];
    const float* Wq   = (const float*)d_in[6];
    const float* gwih = (const float*)d_in[7];
    const float* gwhh = (const float*)d_in[8];
    const float* gbih = (const float*)d_in[9];
    const float* gbhh = (const float*)d_in[10];
    const float* w1   = (const float*)d_in[11];
    const float* b1   = (const float*)d_in[12];
    const float* w2   = (const float*)d_in[13];
    const float* b2   = (const float*)d_in[14];
    const float* ling = (const float*)d_in[15];
    const float* linb = (const float*)d_in[16];
    const float* lsg  = (const float*)d_in[17];
    const float* lsb  = (const float*)d_in[18];
    const float* lfg  = (const float*)d_in[19];
    const float* lfb  = (const float*)d_in[20];

    char* w = (char*)d_ws;
    size_t off = 0;
    auto alloc = [&](size_t bytes) { void* p = w + off; off += (bytes + 255) & ~(size_t)255; return p; };
    bf16* xn_vt  = (bf16*)alloc((size_t)B_ * T_ * D_ * 2);       // xn, later vT
    bf16* kv     = (bf16*)alloc((size_t)B_ * T_ * 1536 * 2);     // [k | v] cols
    float* avis  = (float*)alloc((size_t)B_ * NS * T_ * 4);
    float* pU    = (float*)alloc((size_t)B_ * NCHUNK * S_ * NS * 4);
    float* prs   = (float*)alloc((size_t)B_ * NCHUNK * NS * 4);
    float* vsum  = (float*)alloc((size_t)B_ * S_ * 4);
    float* slotsA = (float*)alloc((size_t)B_ * NS * S_ * 4);
    bf16* slotsA_bf = (bf16*)alloc((size_t)B_ * NS * S_ * 2);
    float* slotsB = (float*)alloc((size_t)B_ * NS * S_ * 4);
    bf16* q_bf   = (bf16*)alloc((size_t)B_ * NS * S_ * 2);
    bf16* upd_bf = (bf16*)alloc((size_t)B_ * NS * S_ * 2);
    bf16* h1_bf  = (bf16*)alloc((size_t)B_ * NS * 4 * S_ * 2);
    bf16* wq_bf  = (bf16*)alloc((size_t)S_ * S_ * 2);
    bf16* wkv_bf = (bf16*)alloc((size_t)1536 * D_ * 2);
    bf16* gwih_bf = (bf16*)alloc((size_t)3 * S_ * S_ * 2);
    bf16* gwhh_bf = (bf16*)alloc((size_t)3 * S_ * S_ * 2);
    bf16* w1_bf  = (bf16*)alloc((size_t)4 * S_ * S_ * 2);
    bf16* w2_bf  = (bf16*)alloc((size_t)S_ * 4 * S_ * 2);
    float* cm_g  = (float*)alloc((size_t)B_ * 256 * 4);

    float* out_slots = (float*)d_out;
    float* out_attn  = out_slots + (size_t)B_ * NS * S_;
    float* out_mask  = out_attn + (size_t)B_ * T_ * NS;

    // weight conversions (one launch)
    cvt_all_kernel<<<39168, 256, 0, stream>>>(Wq, Wk, Wv, gwih, gwhh, w1, w2,
                                              wq_bf, wkv_bf, gwih_bf, gwhh_bf, w1_bf, w2_bf);

    // LN(x) -> xn (bf16)
    ln768_kernel<<<B_ * T_, 256, 0, stream>>>(x, ling, linb, xn_vt);

    // fused k|v projection: [65536 x 1536], XCD-swizzled 1D grid
    gemm128_kernel<<<6144, 256, 0, stream>>>(xn_vt, wkv_bf, kv, B_ * T_, 1536, D_, 12);

    // vT (reuse xn buffer) + vsum
    hipMemsetAsync(vsum, 0, (size_t)B_ * S_ * 4, stream);
    {
        dim3 g(T_ / 32, S_ / 32, B_);
        transpose_vsum_kernel<<<g, 256, 0, stream>>>(kv, xn_vt, vsum);
    }
    bf16* vT = xn_vt;

    init_slots_kernel<<<(B_ * NS * S_) / 256, 256, 0, stream>>>(si, slotsA, slotsA_bf);

    for (int it = 0; it < NIT; ++it) {
        // q = LN(slotsA) @ Wq^T
        {
            dim3 g(16, 12);
            ln_gemm_kernel<<<g, 256, 0, stream>>>(slotsA, lsg, lsb, wq_bf, nullptr,
                                                  q_bf, 768, 0);
        }
        fused_attn_kernel<<<B_ * NCHUNK, 256, 0, stream>>>(q_bf, kv, vT, pU, prs, avis,
                                                           (it == NIT - 1) ? 1 : 0);
        attn_reduce_kernel<<<(B_ * NS * S_) / 256, 256, 0, stream>>>(pU, prs, vsum, upd_bf);
        {
            dim3 g(16, 12);
            fused_gru_kernel<<<g, 256, 0, stream>>>(upd_bf, slotsA_bf, gwih_bf, gwhh_bf,
                                                    gbih, gbhh, slotsA, slotsB);
        }
        // h1 = relu(LN(slotsB) @ w1^T + b1)
        {
            dim3 g(16, 48);
            ln_gemm_kernel<<<g, 256, 0, stream>>>(slotsB, lfg, lfb, w1_bf, b1,
                                                  h1_bf, 3072, 1);
        }
        // slotsA = slotsB + h1 @ w2^T + b2
        {
            dim3 g(16, 12);
            mlp_out_kernel<<<g, 256, 0, stream>>>(h1_bf, w2_bf, b2, slotsB,
                                                  slotsA, slotsA_bf);
        }
    }

    cluster_kernel<<<B_, 256, 0, stream>>>(slotsA, out_slots, out_mask, cm_g);
    {
        dim3 g(T_ / 256, B_);
        cattn_kernel<<<g, 256, 0, stream>>>(avis, cm_g, out_attn);
    }
}

// Round 6
// 1464.380 us; speedup vs baseline: 1.4293x; 1.2569x over previous
//
#include <hip/hip_runtime.h>
#include <hip/hip_bf16.h>

typedef __hip_bfloat16 bf16;
typedef __attribute__((ext_vector_type(4))) float f32x4;
typedef __attribute__((ext_vector_type(8))) short s16x8;
typedef unsigned int u32;
typedef unsigned short u16;

#define B_ 16
#define T_ 4096
#define D_ 768
#define S_ 768
#define NS 16
#define NIT 9
#define NCHUNK 16
#define TCH 256
#define EPS 1e-8f
#define SCALE 0.036084391824351615f  /* 768^-0.5 */

__device__ __forceinline__ void gld16(const void* g, void* l) {
    __builtin_amdgcn_global_load_lds((const __attribute__((address_space(1))) u32*)g,
                                     (__attribute__((address_space(3))) u32*)l, 16, 0, 0);
}

__device__ __forceinline__ u16 bfbits(float x) {
    bf16 h = __float2bfloat16(x);
    return *reinterpret_cast<u16*>(&h);
}

// ---------------------------------------------------------------------------
// All weight conversions in one launch. wkv = [Wk rows; Wv rows] (1536 x 768).
__global__ void __launch_bounds__(256) cvt_all_kernel(
    const float* __restrict__ wq, const float* __restrict__ wk, const float* __restrict__ wv,
    const float* __restrict__ gwih, const float* __restrict__ gwhh,
    const float* __restrict__ w1, const float* __restrict__ w2,
    bf16* __restrict__ wq_b, bf16* __restrict__ wkv_b,
    bf16* __restrict__ gwih_b, bf16* __restrict__ gwhh_b,
    bf16* __restrict__ w1_b, bf16* __restrict__ w2_b)
{
    int i = blockIdx.x * 256 + threadIdx.x;
    const int NW = 589824, NG = 1769472, NM = 2359296;
    if (i < NW) { wq_b[i] = __float2bfloat16(wq[i]); return; }
    i -= NW;
    if (i < NW) { wkv_b[i] = __float2bfloat16(wk[i]); return; }
    i -= NW;
    if (i < NW) { wkv_b[NW + i] = __float2bfloat16(wv[i]); return; }
    i -= NW;
    if (i < NG) { gwih_b[i] = __float2bfloat16(gwih[i]); return; }
    i -= NG;
    if (i < NG) { gwhh_b[i] = __float2bfloat16(gwhh[i]); return; }
    i -= NG;
    if (i < NM) { w1_b[i] = __float2bfloat16(w1[i]); return; }
    i -= NM;
    w2_b[i] = __float2bfloat16(w2[i]);
}

// ---------------------------------------------------------------------------
// LayerNorm rows of 768, fp32 in -> bf16 out. One 256-thread block per row.
__global__ void __launch_bounds__(256) ln768_kernel(
    const float* __restrict__ x, const float* __restrict__ g,
    const float* __restrict__ bta, bf16* __restrict__ out)
{
    int row = blockIdx.x;
    int tid = threadIdx.x;
    const float* xr = x + (size_t)row * 768;
    float v0 = xr[tid], v1 = xr[tid + 256], v2 = xr[tid + 512];
    float s = v0 + v1 + v2;
    int lane = tid & 63, wid = tid >> 6;
    #pragma unroll
    for (int off = 32; off; off >>= 1) s += __shfl_down(s, off);
    __shared__ float red[4];
    __shared__ float sh_mu, sh_rs;
    if (lane == 0) red[wid] = s;
    __syncthreads();
    if (tid == 0) sh_mu = (red[0] + red[1] + red[2] + red[3]) * (1.f / 768.f);
    __syncthreads();
    float mu = sh_mu;
    float d0 = v0 - mu, d1 = v1 - mu, d2 = v2 - mu;
    float q = d0 * d0 + d1 * d1 + d2 * d2;
    #pragma unroll
    for (int off = 32; off; off >>= 1) q += __shfl_down(q, off);
    if (lane == 0) red[wid] = q;
    __syncthreads();
    if (tid == 0) sh_rs = rsqrtf((red[0] + red[1] + red[2] + red[3]) * (1.f / 768.f) + 1e-5f);
    __syncthreads();
    float rs = sh_rs;
    bf16* orow = out + (size_t)row * 768;
    orow[tid]       = __float2bfloat16(d0 * rs * g[tid]       + bta[tid]);
    orow[tid + 256] = __float2bfloat16(d1 * rs * g[tid + 256] + bta[tid + 256]);
    orow[tid + 512] = __float2bfloat16(d2 * rs * g[tid + 512] + bta[tid + 512]);
}

// ---------------------------------------------------------------------------
// 256x128 NT GEMM for kv projection. 8 waves, 48KB LDS, 3 blocks/CU.
// N-tiles 0..5 -> k rows (row-major), 6..11 -> v written TRANSPOSED to vT + vsum.
// C bounced through LDS for coalesced 16B stores. XCD-swizzled 1D grid.
__global__ void __launch_bounds__(512) gemm256_kernel(
    const bf16* __restrict__ A, const bf16* __restrict__ W,
    bf16* __restrict__ kout, bf16* __restrict__ vTout, float* __restrict__ vsum)
{
    __shared__ char smem[49152];           // As 32KB | Bs 16KB ; epilogue: Ct 64x132 f32
    __shared__ float vs_l[128];
    bf16* As = (bf16*)smem;
    bf16* Bs = (bf16*)(smem + 32768);
    int tid = threadIdx.x, lane = tid & 63, wid = tid >> 6;
    int bid = blockIdx.x;
    int xcd = bid & 7, idx = bid >> 3;
    int mt = xcd * 32 + idx / 12;
    int nt = idx % 12;
    int bm0 = mt * 256, bn0 = nt * 128;
    int wr = wid >> 1, wc = wid & 1;
    int g = lane >> 4, r15 = lane & 15;
    const f32x4 vzero = {0.f, 0.f, 0.f, 0.f};
    f32x4 acc[4][4];
    #pragma unroll
    for (int m = 0; m < 4; ++m)
        #pragma unroll
        for (int n = 0; n < 4; ++n) acc[m][n] = vzero;

    for (int kt = 0; kt < 768; kt += 64) {
        __syncthreads();
        #pragma unroll
        for (int i = 0; i < 4; ++i) {           // A: 2048 segs
            int s0 = i * 512 + wid * 64;
            int o = (s0 + lane) * 16;
            int r = o >> 7, cb = o & 127;
            int cbs = cb ^ ((r & 7) << 4);
            gld16(A + (size_t)(bm0 + r) * 768 + kt + (cbs >> 1), (char*)As + (size_t)s0 * 16);
        }
        #pragma unroll
        for (int i = 0; i < 2; ++i) {           // B: 1024 segs
            int s0 = i * 512 + wid * 64;
            int o = (s0 + lane) * 16;
            int r = o >> 7, cb = o & 127;
            int cbs = cb ^ ((r & 7) << 4);
            gld16(W + (size_t)(bn0 + r) * 768 + kt + (cbs >> 1), (char*)Bs + (size_t)s0 * 16);
        }
        asm volatile("s_waitcnt vmcnt(0)" ::: "memory");
        __syncthreads();
        #pragma unroll
        for (int kk2 = 0; kk2 < 2; ++kk2) {
            s16x8 af[4], bfr[4];
            #pragma unroll
            for (int m = 0; m < 4; ++m) {
                int r = wr * 64 + m * 16 + r15;
                int p = r * 128 + ((kk2 * 64 + g * 16) ^ ((r & 7) << 4));
                af[m] = *(const s16x8*)((const char*)As + p);
            }
            #pragma unroll
            for (int n = 0; n < 4; ++n) {
                int r = wc * 64 + n * 16 + r15;
                int p = r * 128 + ((kk2 * 64 + g * 16) ^ ((r & 7) << 4));
                bfr[n] = *(const s16x8*)((const char*)Bs + p);
            }
            #pragma unroll
            for (int m = 0; m < 4; ++m)
                #pragma unroll
                for (int n = 0; n < 4; ++n)
                    acc[m][n] = __builtin_amdgcn_mfma_f32_16x16x32_bf16(af[m], bfr[n], acc[m][n], 0, 0, 0);
        }
    }

    // ---- epilogue: bounce 64-row quarters through LDS ----
    bool is_v = (bn0 >= 768);
    float* Ct = (float*)smem;                  // [64][132] f32 = 33792B
    int bq = bm0 >> 12;                        // batch
    int tloc = bm0 & 4095;
    if (is_v && tid < 128) vs_l[tid] = 0.f;
    #pragma unroll
    for (int q = 0; q < 4; ++q) {
        __syncthreads();
        if (wr == q) {
            #pragma unroll
            for (int m = 0; m < 4; ++m)
                #pragma unroll
                for (int n = 0; n < 4; ++n)
                    #pragma unroll
                    for (int j = 0; j < 4; ++j)
                        Ct[(m * 16 + g * 4 + j) * 132 + wc * 64 + n * 16 + r15] = acc[m][n][j];
        }
        __syncthreads();
        if (!is_v) {
            int r = tid >> 3, cq = tid & 7;    // 64 rows x 8 col-groups of 16
            u16 tmp[16];
            #pragma unroll
            for (int i = 0; i < 16; ++i) tmp[i] = bfbits(Ct[r * 132 + cq * 16 + i]);
            s16x8 o0, o1;
            #pragma unroll
            for (int i = 0; i < 8; ++i) { o0[i] = (short)tmp[i]; o1[i] = (short)tmp[8 + i]; }
            bf16* dst = kout + (size_t)(bm0 + q * 64 + r) * 768 + bn0 + cq * 16;
            *(s16x8*)dst = o0;
            *(s16x8*)(dst + 8) = o1;
        } else {
            int d = tid >> 2, tq = tid & 3;    // 128 d-rows x 4 t-groups of 16
            float ssum = 0.f;
            u16 tmp[16];
            #pragma unroll
            for (int i = 0; i < 16; ++i) {
                float f = Ct[(tq * 16 + i) * 132 + d];
                ssum += f;
                tmp[i] = bfbits(f);
            }
            s16x8 o0, o1;
            #pragma unroll
            for (int i = 0; i < 8; ++i) { o0[i] = (short)tmp[i]; o1[i] = (short)tmp[8 + i]; }
            bf16* dst = vTout + ((size_t)bq * 768 + (bn0 - 768) + d) * (size_t)T_
                        + tloc + q * 64 + tq * 16;
            *(s16x8*)dst = o0;
            *(s16x8*)(dst + 8) = o1;
            atomicAdd(&vs_l[d], ssum);
        }
    }
    if (is_v) {
        __syncthreads();
        if (tid < 128) atomicAdd(vsum + bq * 768 + (bn0 - 768) + tid, vs_l[tid]);
    }
}

// ---------------------------------------------------------------------------
__global__ void init_slots_kernel(const float* __restrict__ si,
                                  float* __restrict__ slots, bf16* __restrict__ slots_bf)
{
    int idx = blockIdx.x * 256 + threadIdx.x;  // 256*768
    float v = si[idx % (NS * S_)];
    slots[idx] = v;
    slots_bf[idx] = __float2bfloat16(v);
}

// ---------------------------------------------------------------------------
// Fused LN(16 rows) + NT GEMM with double-buffered staged W chunks.
// grid (M/16, N/64). W: [N][768] bf16. out bf16 [M][N].
__global__ void __launch_bounds__(256) ln_gemm_kernel(
    const float* __restrict__ xin, const float* __restrict__ gam, const float* __restrict__ bet,
    const bf16* __restrict__ W, const float* __restrict__ bias,
    bf16* __restrict__ out, int N, int relu)
{
    __shared__ bf16 As[16 * 768];     // 24KB, rows 1536B XOR-swizzled
    __shared__ bf16 Ws[2][64 * 64];   // 2 x 8KB, rows 128B XOR-swizzled
    int tid = threadIdx.x;
    int bx = blockIdx.x, bn0 = blockIdx.y * 64;
    int row = tid >> 4, li = tid & 15;
    const float* xr = xin + (size_t)(bx * 16 + row) * 768;
    float vals[48];
    float s = 0.f;
    #pragma unroll
    for (int i = 0; i < 48; ++i) { vals[i] = xr[li + i * 16]; s += vals[i]; }
    #pragma unroll
    for (int m = 1; m < 16; m <<= 1) s += __shfl_xor(s, m);
    float mu = s * (1.f / 768.f);
    float q = 0.f;
    #pragma unroll
    for (int i = 0; i < 48; ++i) { float d = vals[i] - mu; q += d * d; }
    #pragma unroll
    for (int m = 1; m < 16; m <<= 1) q += __shfl_xor(q, m);
    float rs = rsqrtf(q * (1.f / 768.f) + 1e-5f);
    #pragma unroll
    for (int i = 0; i < 48; ++i) {
        int c = li + i * 16;
        float v = (vals[i] - mu) * rs * gam[c] + bet[c];
        *(u16*)((char*)As + row * 1536 + ((c * 2) ^ ((row & 7) << 4))) = bfbits(v);
    }
    int lane = tid & 63, wid = tid >> 6;
    int g = lane >> 4, s15 = lane & 15;
    auto stageW = [&](int kt, int buf) {
        #pragma unroll
        for (int i = 0; i < 2; ++i) {
            int s0 = i * 256 + wid * 64;
            int o = (s0 + lane) * 16;
            int r = o >> 7, cb = o & 127;
            int cbs = cb ^ ((r & 7) << 4);
            gld16(W + (size_t)(bn0 + r) * 768 + kt + (cbs >> 1),
                  (char*)Ws[buf] + (size_t)s0 * 16);
        }
    };
    stageW(0, 0);
    asm volatile("s_waitcnt vmcnt(0)" ::: "memory");
    __syncthreads();
    f32x4 acc = {0.f, 0.f, 0.f, 0.f};
    int rb = wid * 16 + s15;
    for (int t = 0; t < 12; ++t) {
        int cur = t & 1;
        if (t < 11) stageW((t + 1) * 64, cur ^ 1);
        #pragma unroll
        for (int kk2 = 0; kk2 < 2; ++kk2) {
            int kabs = t * 64 + kk2 * 32;
            s16x8 af = *(const s16x8*)((const char*)As + s15 * 1536 +
                                       ((kabs * 2 + g * 16) ^ ((s15 & 7) << 4)));
            s16x8 bf_ = *(const s16x8*)((const char*)Ws[cur] + rb * 128 +
                                        ((kk2 * 64 + g * 16) ^ ((rb & 7) << 4)));
            acc = __builtin_amdgcn_mfma_f32_16x16x32_bf16(af, bf_, acc, 0, 0, 0);
        }
        asm volatile("s_waitcnt vmcnt(0)" ::: "memory");
        __syncthreads();
    }
    int cn = bn0 + rb;
    float bv = bias ? bias[cn] : 0.f;
    #pragma unroll
    for (int j = 0; j < 4; ++j) {
        float val = acc[j] + bv;
        if (relu) val = fmaxf(val, 0.f);
        out[(size_t)(bx * 16 + g * 4 + j) * N + cn] = __float2bfloat16(val);
    }
}

// ---------------------------------------------------------------------------
// Skinny NT GEMM body: BM=16, BN=64, BK=64, LDS-staged (round-2 proven).
// out = act(acc + bias + Cin); writes Cf (f32) and/or Cb (bf16).
__device__ __forceinline__ void skinny_body(
    const bf16* A, const bf16* Bm, const float* bias, const float* Cin,
    float* Cf, bf16* Cb, int N, int K, int bm0, int bn0, int relu,
    bf16* As, bf16* Bs)
{
    int tid = threadIdx.x, lane = tid & 63, wid = tid >> 6;
    int g = lane >> 4, r15 = lane & 15;
    f32x4 acc = {0.f, 0.f, 0.f, 0.f};
    for (int kt = 0; kt < K; kt += 64) {
        __syncthreads();
        #pragma unroll
        for (int i = 0; i < 3; ++i) {
            int s0 = i * 256 + wid * 64;
            if (s0 < 640) {
                int o = (s0 + lane) * 16;
                if (o < 2048) {
                    int r = o >> 7, cb = o & 127;
                    int cbs = cb ^ ((r & 7) << 4);
                    gld16(A + (size_t)(bm0 + r) * K + kt + (cbs >> 1), (char*)As + (size_t)s0 * 16);
                } else {
                    int ob = o - 2048;
                    int r = ob >> 7, cb = ob & 127;
                    int cbs = cb ^ ((r & 7) << 4);
                    gld16(Bm + (size_t)(bn0 + r) * K + kt + (cbs >> 1),
                          (char*)Bs + (size_t)(s0 * 16 - 2048));
                }
            }
        }
        asm volatile("s_waitcnt vmcnt(0)" ::: "memory");
        __syncthreads();
        #pragma unroll
        for (int kk = 0; kk < 64; kk += 32) {
            int pa = r15 * 128 + ((kk * 2 + g * 16) ^ ((r15 & 7) << 4));
            s16x8 af = *(const s16x8*)((const char*)As + pa);
            int rb = wid * 16 + r15;
            int pb = rb * 128 + ((kk * 2 + g * 16) ^ ((rb & 7) << 4));
            s16x8 bfr = *(const s16x8*)((const char*)Bs + pb);
            acc = __builtin_amdgcn_mfma_f32_16x16x32_bf16(af, bfr, acc, 0, 0, 0);
        }
    }
    int cn = bn0 + wid * 16 + r15;
    float bv = bias ? bias[cn] : 0.f;
    #pragma unroll
    for (int j = 0; j < 4; ++j) {
        int cm = bm0 + g * 4 + j;
        size_t ci = (size_t)cm * N + cn;
        float val = acc[j] + bv;
        if (Cin) val += Cin[ci];
        if (relu) val = fmaxf(val, 0.f);
        if (Cf) Cf[ci] = val;
        if (Cb) Cb[ci] = __float2bfloat16(val);
    }
}

// mlp2: slotsA = slotsB + h1@W2^T + b2   (grid (16,12))
__global__ void __launch_bounds__(256) mlp2_kernel(
    const bf16* __restrict__ h1, const bf16* __restrict__ W2, const float* __restrict__ b2,
    const float* __restrict__ slotsB, float* __restrict__ slotsA, bf16* __restrict__ slotsA_bf)
{
    __shared__ bf16 As[16 * 64];
    __shared__ bf16 Bs[64 * 64];
    skinny_body(h1, W2, b2, slotsB, slotsA, slotsA_bf, 768, 3072,
                blockIdx.x * 16, blockIdx.y * 64, 0, As, Bs);
}

// gi|gh in one launch: y<36 -> gi = upd@Wih^T + bih ; y>=36 -> gh = slots@Whh^T + bhh
__global__ void __launch_bounds__(256) gru_gemm_kernel(
    const bf16* __restrict__ upd, const bf16* __restrict__ slots_bf,
    const bf16* __restrict__ Wih, const bf16* __restrict__ Whh,
    const float* __restrict__ bih, const float* __restrict__ bhh,
    float* __restrict__ gi, float* __restrict__ gh)
{
    __shared__ bf16 As[16 * 64];
    __shared__ bf16 Bs[64 * 64];
    int y = blockIdx.y;
    if (y < 36)
        skinny_body(upd, Wih, bih, nullptr, gi, nullptr, 2304, 768,
                    blockIdx.x * 16, y * 64, 0, As, Bs);
    else
        skinny_body(slots_bf, Whh, bhh, nullptr, gh, nullptr, 2304, 768,
                    blockIdx.x * 16, (y - 36) * 64, 0, As, Bs);
}

// ---------------------------------------------------------------------------
// Two-pass fused attention per (batch, 256-t chunk), double-buffered slices.
// Pass1: QK^T + softmax over slots -> a in LDS (+avis). Pass2: U^T += vT@a^T.
__global__ void __launch_bounds__(256) fused_attn_kernel(
    const bf16* __restrict__ q_bf, const bf16* __restrict__ k_bf, const bf16* __restrict__ vT,
    float* __restrict__ pU, float* __restrict__ prs, float* __restrict__ avis, int write_avis)
{
    __shared__ char smem[131072];
    bf16* ks0 = (bf16*)smem;                 // 48KB (pass2: vs0)
    bf16* ks1 = (bf16*)(smem + 49152);       // 48KB (pass2: vs1)
    bf16* qs  = (bf16*)(smem + 98304);       // 24KB
    char* aL  = smem + 122880;               // 8KB: [8 slices][16s][64B]
    __shared__ float rsw[2][16];
    int tid = threadIdx.x, lane = tid & 63, wid = tid >> 6;
    int b = blockIdx.x >> 4, chunk = blockIdx.x & 15;
    int t0 = chunk * TCH;
    int g = lane >> 4, s15 = lane & 15;
    const bf16* qb  = q_bf + (size_t)b * 16 * 768;
    const bf16* kb  = k_bf + (size_t)b * T_ * 768;
    const bf16* vtb = vT + (size_t)b * 768 * T_;

    auto stage_k = [&](int tb, bf16* dst) {
        #pragma unroll
        for (int i = 0; i < 12; ++i) {
            int s0 = i * 256 + wid * 64;
            int o = (s0 + lane) * 16;
            int r = o / 1536, cb = o % 1536;
            int cbs = cb ^ ((r & 7) << 4);
            gld16(kb + (size_t)(tb + r) * 768 + (cbs >> 1), (char*)dst + (size_t)s0 * 16);
        }
    };
    auto stage_v = [&](int tb, bf16* dst) {
        #pragma unroll
        for (int i = 0; i < 12; ++i) {
            int s0 = i * 256 + wid * 64;
            int o = (s0 + lane) * 16;
            int d = o >> 6, cb = o & 63;
            int cbs = cb ^ ((d & 3) << 4);
            gld16(vtb + (size_t)d * T_ + tb + (cbs >> 1), (char*)dst + (size_t)s0 * 16);
        }
    };

    // stage q + first k slice
    #pragma unroll
    for (int i = 0; i < 6; ++i) {
        int s0 = i * 256 + wid * 64;
        int o = (s0 + lane) * 16;
        int r = o / 1536, cb = o % 1536;
        int cbs = cb ^ ((r & 7) << 4);
        gld16(qb + (size_t)r * 768 + (cbs >> 1), (char*)qs + (size_t)s0 * 16);
    }
    stage_k(t0, ks0);
    asm volatile("s_waitcnt vmcnt(0)" ::: "memory");
    __syncthreads();

    const f32x4 vzero = {0.f, 0.f, 0.f, 0.f};
    float rs_acc = 0.f;

    // ---- pass 1: QK^T + softmax ----
    for (int ts = 0; ts < 8; ++ts) {
        bf16* cur = (ts & 1) ? ks1 : ks0;
        bf16* nxt = (ts & 1) ? ks0 : ks1;
        if (ts < 7) stage_k(t0 + (ts + 1) * 32, nxt);
        if (wid < 2) {
            f32x4 dacc = vzero;
            #pragma unroll
            for (int kk = 0; kk < 768; kk += 32) {
                int rk = wid * 16 + s15;
                int pk = rk * 1536 + ((kk * 2 + g * 16) ^ ((rk & 7) << 4));
                s16x8 kf = *(const s16x8*)((const char*)cur + pk);
                int pq = s15 * 1536 + ((kk * 2 + g * 16) ^ ((s15 & 7) << 4));
                s16x8 qf = *(const s16x8*)((const char*)qs + pq);
                dacc = __builtin_amdgcn_mfma_f32_16x16x32_bf16(kf, qf, dacc, 0, 0, 0);
            }
            float d0 = dacc[0] * SCALE, d1 = dacc[1] * SCALE,
                  d2 = dacc[2] * SCALE, d3 = dacc[3] * SCALE;
            float m0 = d0, m1 = d1, m2 = d2, m3 = d3;
            #pragma unroll
            for (int off = 1; off < 16; off <<= 1) {
                m0 = fmaxf(m0, __shfl_xor(m0, off));
                m1 = fmaxf(m1, __shfl_xor(m1, off));
                m2 = fmaxf(m2, __shfl_xor(m2, off));
                m3 = fmaxf(m3, __shfl_xor(m3, off));
            }
            float e0 = expf(d0 - m0), e1 = expf(d1 - m1), e2 = expf(d2 - m2), e3 = expf(d3 - m3);
            float q0 = e0, q1 = e1, q2 = e2, q3 = e3;
            #pragma unroll
            for (int off = 1; off < 16; off <<= 1) {
                q0 += __shfl_xor(q0, off);
                q1 += __shfl_xor(q1, off);
                q2 += __shfl_xor(q2, off);
                q3 += __shfl_xor(q3, off);
            }
            float a0 = e0 / q0, a1 = e1 / q1, a2 = e2 / q2, a3 = e3 / q3;
            rs_acc += a0 + a1 + a2 + a3;
            int tl = wid * 16 + g * 4;
            ushort2 p0, p1;
            p0.x = bfbits(a0); p0.y = bfbits(a1);
            p1.x = bfbits(a2); p1.y = bfbits(a3);
            int sw = (s15 & 3) << 4;
            char* aS = aL + ts * 1024;
            *(ushort2*)(aS + s15 * 64 + ((tl * 2) ^ sw))       = p0;
            *(ushort2*)(aS + s15 * 64 + (((tl + 2) * 2) ^ sw)) = p1;
            if (write_avis) {
                f32x4 w = {a0, a1, a2, a3};
                *(f32x4*)(avis + (size_t)(b * 16 + s15) * T_ + t0 + ts * 32 + tl) = w;
            }
        }
        asm volatile("s_waitcnt vmcnt(0)" ::: "memory");
        __syncthreads();
    }

    // ---- pass 2: PV ----
    f32x4 uacc[12];
    #pragma unroll
    for (int i = 0; i < 12; ++i) uacc[i] = vzero;
    stage_v(t0, ks0);
    asm volatile("s_waitcnt vmcnt(0)" ::: "memory");
    __syncthreads();
    for (int ts = 0; ts < 8; ++ts) {
        bf16* cur = (ts & 1) ? ks1 : ks0;
        bf16* nxt = (ts & 1) ? ks0 : ks1;
        if (ts < 7) stage_v(t0 + (ts + 1) * 32, nxt);
        {
            int pa = ts * 1024 + s15 * 64 + ((g * 16) ^ ((s15 & 3) << 4));
            s16x8 afr = *(const s16x8*)(aL + pa);
            #pragma unroll
            for (int i = 0; i < 12; ++i) {
                int d = (wid * 12 + i) * 16 + s15;
                int pv = d * 64 + ((g * 16) ^ ((d & 3) << 4));
                s16x8 vf = *(const s16x8*)((const char*)cur + pv);
                uacc[i] = __builtin_amdgcn_mfma_f32_16x16x32_bf16(vf, afr, uacc[i], 0, 0, 0);
            }
        }
        asm volatile("s_waitcnt vmcnt(0)" ::: "memory");
        __syncthreads();
    }

    // write partial U^T: [b][chunk][d][s]
    float* pUb = pU + (size_t)(b * 16 + chunk) * 768 * 16;
    #pragma unroll
    for (int i = 0; i < 12; ++i) {
        int dbase = (wid * 12 + i) * 16 + g * 4;
        #pragma unroll
        for (int j = 0; j < 4; ++j)
            pUb[(size_t)(dbase + j) * 16 + s15] = uacc[i][j];
    }
    rs_acc += __shfl_xor(rs_acc, 16);
    rs_acc += __shfl_xor(rs_acc, 32);
    if (wid < 2 && lane < 16) rsw[wid][s15] = rs_acc;
    __syncthreads();
    if (tid < 16) prs[(b * 16 + chunk) * 16 + tid] = rsw[0][tid] + rsw[1][tid];
}

// reduce partials: upd[b][s][d] = (sum_c pU + EPS*vsum[b][d]) / (sum_c prs + T*EPS)
__global__ void __launch_bounds__(256) attn_reduce_kernel(
    const float* __restrict__ pU, const float* __restrict__ prs,
    const float* __restrict__ vsum, bf16* __restrict__ upd)
{
    int idx = blockIdx.x * 256 + threadIdx.x;   // 16*16*768
    int d = idx % 768;
    int s = (idx / 768) & 15;
    int b = idx / (768 * 16);
    float su = 0.f;
    #pragma unroll
    for (int c = 0; c < 16; ++c) su += pU[((size_t)(b * 16 + c) * 768 + d) * 16 + s];
    float rs = 0.f;
    #pragma unroll
    for (int c = 0; c < 16; ++c) rs += prs[(b * 16 + c) * 16 + s];
    float val = (su + EPS * vsum[b * 768 + d]) / (rs + T_ * EPS);
    upd[idx] = __float2bfloat16(val);
}

// ---------------------------------------------------------------------------
// GRU gates: slotsB = GRUCell(upd, slotsA)
__global__ void __launch_bounds__(256) gru_gates_kernel(
    const float* __restrict__ gi, const float* __restrict__ gh,
    const float* __restrict__ slotsA, float* __restrict__ slotsB)
{
    int idx = blockIdx.x * 256 + threadIdx.x;
    int r = idx / 768, c = idx - r * 768;
    const float* gir = gi + (size_t)r * 2304;
    const float* ghr = gh + (size_t)r * 2304;
    float ir = gir[c], iz = gir[768 + c], inn = gir[1536 + c];
    float hr = ghr[c], hz = ghr[768 + c], hn  = ghr[1536 + c];
    float rg = 1.f / (1.f + expf(-(ir + hr)));
    float z  = 1.f / (1.f + expf(-(iz + hz)));
    float n  = tanhf(inn + rg * hn);
    float h  = slotsA[idx];
    slotsB[idx] = (1.f - z) * n + z * h;
}

// ---------------------------------------------------------------------------
// Clustering epilogue
__global__ void __launch_bounds__(256) cluster_kernel(
    const float* __restrict__ slots, float* __restrict__ out_slots,
    float* __restrict__ out_mask, float* __restrict__ cm_g)
{
    int b = blockIdx.x;
    __shared__ float s[16][768];
    __shared__ float inv[16];
    __shared__ float adj[16][16], tmp[16][16], cw[16][16];
    __shared__ int reset_s;
    const float* sb = slots + (size_t)b * 16 * 768;
    for (int i = threadIdx.x; i < 16 * 768; i += 256) s[i / 768][i % 768] = sb[i];
    __syncthreads();
    if (threadIdx.x < 16) {
        float q = 0.f;
        for (int d = 0; d < 768; ++d) q += s[threadIdx.x][d] * s[threadIdx.x][d];
        inv[threadIdx.x] = 1.f / fmaxf(sqrtf(q), 1e-12f);
    }
    __syncthreads();
    int n = threadIdx.x >> 4, m = threadIdx.x & 15;
    float dot = 0.f;
    for (int d = 0; d < 768; ++d) dot += s[n][d] * s[m][d];
    dot *= inv[n] * inv[m];
    adj[n][m] = ((1.f - dot) < 0.5f) ? 1.f : 0.f;
    __syncthreads();
    #pragma unroll
    for (int it = 0; it < 4; ++it) {
        float t = 0.f;
        #pragma unroll
        for (int j = 0; j < 16; ++j) t += adj[n][j] * adj[j][m];
        tmp[n][m] = fminf(t, 1.f);
        __syncthreads();
        adj[n][m] = tmp[n][m];
        __syncthreads();
    }
    if (threadIdx.x < 16) {
        int mm = threadIdx.x;
        float run = 0.f;
        for (int nn = 0; nn < 16; ++nn) {
            run += adj[nn][mm];
            tmp[nn][mm] = adj[nn][mm] * ((run <= 1.f) ? 1.f : 0.f);
        }
    }
    __syncthreads();
    if (threadIdx.x == 0) {
        int cnt = 0;
        for (int nn = 0; nn < 16; ++nn) {
            bool any = false;
            for (int j = 0; j < 16; ++j) any = any || (tmp[nn][j] > 0.f);
            cnt += any ? 1 : 0;
        }
        reset_s = (cnt < 3) ? 1 : 0;
    }
    __syncthreads();
    if (reset_s) tmp[n][m] = (n == m) ? 1.f : 0.f;
    __syncthreads();
    if (threadIdx.x < 16) {
        float rs = 0.f;
        for (int j = 0; j < 16; ++j) rs += tmp[threadIdx.x][j];
        rs = fmaxf(rs, 1.f);
        for (int j = 0; j < 16; ++j) cw[threadIdx.x][j] = tmp[threadIdx.x][j] / rs;
        bool any = false;
        for (int j = 0; j < 16; ++j) any = any || (tmp[threadIdx.x][j] > 0.f);
        out_mask[b * 16 + threadIdx.x] = any ? 1.f : 0.f;
    }
    cm_g[b * 256 + threadIdx.x] = tmp[n][m];
    __syncthreads();
    for (int i = threadIdx.x; i < 16 * 768; i += 256) {
        int nn = i / 768, d = i - nn * 768;
        float acc = 0.f;
        #pragma unroll
        for (int j = 0; j < 16; ++j) acc += cw[nn][j] * s[j][d];
        out_slots[(size_t)b * 16 * 768 + i] = acc;
    }
}

__global__ void __launch_bounds__(256) cattn_kernel(
    const float* __restrict__ av, const float* __restrict__ cm_g, float* __restrict__ out_attn)
{
    int b = blockIdx.y;
    int t = blockIdx.x * 256 + threadIdx.x;
    __shared__ float cm[16][16];
    cm[threadIdx.x >> 4][threadIdx.x & 15] = cm_g[b * 256 + threadIdx.x];
    __syncthreads();
    float avv[16];
    #pragma unroll
    for (int j = 0; j < 16; ++j) avv[j] = av[((size_t)b * 16 + j) * T_ + t];
    #pragma unroll
    for (int i = 0; i < 16; ++i) {
        float acc = 0.f;
        #pragma unroll
        for (int j = 0; j < 16; ++j) acc += cm[i][j] * avv[j];
        out_attn[((size_t)b * T_ + t) * 16 + i] = acc;
    }
}

// ---------------------------------------------------------------------------
extern "C" void kernel_launch(void* const* d_in, const int* in_sizes, int n_in,
                              void* d_out, int out_size, void* d_ws, size_t ws_size,
                              hipStream_t stream)
{
    const float* x    = (const float*)d_in[0];
    const float* si   = (const float*)d_in[3];
    const float* Wk   = (const float*)d_in[4];
    const float* Wv   = (const float*)d_in[5];
    const float* Wq   = (const float*)d_in[6];
    const float* gwih = (const float*)d_in[7];
    const float* gwhh = (const float*)d_in[8];
    const float* gbih = (const float*)d_in[9];
    const float* gbhh = (const float*)d_in[10];
    const float* w1   = (const float*)d_in[11];
    const float* b1   = (const float*)d_in[12];
    const float* w2   = (const float*)d_in[13];
    const float* b2   = (const float*)d_in[14];
    const float* ling = (const float*)d_in[15];
    const float* linb = (const float*)d_in[16];
    const float* lsg  = (const float*)d_in[17];
    const float* lsb  = (const float*)d_in[18];
    const float* lfg  = (const float*)d_in[19];
    const float* lfb  = (const float*)d_in[20];

    char* w = (char*)d_ws;
    size_t off = 0;
    auto alloc = [&](size_t bytes) { void* p = w + off; off += (bytes + 255) & ~(size_t)255; return p; };
    bf16* xn     = (bf16*)alloc((size_t)B_ * T_ * D_ * 2);
    bf16* k_bf   = (bf16*)alloc((size_t)B_ * T_ * S_ * 2);
    bf16* vT     = (bf16*)alloc((size_t)B_ * S_ * T_ * 2);
    float* avis  = (float*)alloc((size_t)B_ * NS * T_ * 4);
    float* pU    = (float*)alloc((size_t)B_ * NCHUNK * S_ * NS * 4);
    float* prs   = (float*)alloc((size_t)B_ * NCHUNK * NS * 4);
    float* vsum  = (float*)alloc((size_t)B_ * S_ * 4);
    float* slotsA = (float*)alloc((size_t)B_ * NS * S_ * 4);
    bf16* slotsA_bf = (bf16*)alloc((size_t)B_ * NS * S_ * 2);
    float* slotsB = (float*)alloc((size_t)B_ * NS * S_ * 4);
    bf16* q_bf   = (bf16*)alloc((size_t)B_ * NS * S_ * 2);
    bf16* upd_bf = (bf16*)alloc((size_t)B_ * NS * S_ * 2);
    float* gi    = (float*)alloc((size_t)B_ * NS * 3 * S_ * 4);
    float* gh    = (float*)alloc((size_t)B_ * NS * 3 * S_ * 4);
    bf16* h1_bf  = (bf16*)alloc((size_t)B_ * NS * 4 * S_ * 2);
    bf16* wq_bf  = (bf16*)alloc((size_t)S_ * S_ * 2);
    bf16* wkv_bf = (bf16*)alloc((size_t)1536 * D_ * 2);
    bf16* gwih_bf = (bf16*)alloc((size_t)3 * S_ * S_ * 2);
    bf16* gwhh_bf = (bf16*)alloc((size_t)3 * S_ * S_ * 2);
    bf16* w1_bf  = (bf16*)alloc((size_t)4 * S_ * S_ * 2);
    bf16* w2_bf  = (bf16*)alloc((size_t)S_ * 4 * S_ * 2);
    float* cm_g  = (float*)alloc((size_t)B_ * 256 * 4);

    float* out_slots = (float*)d_out;
    float* out_attn  = out_slots + (size_t)B_ * NS * S_;
    float* out_mask  = out_attn + (size_t)B_ * T_ * NS;

    cvt_all_kernel<<<39168, 256, 0, stream>>>(Wq, Wk, Wv, gwih, gwhh, w1, w2,
                                              wq_bf, wkv_bf, gwih_bf, gwhh_bf, w1_bf, w2_bf);

    // LN(x) -> xn
    ln768_kernel<<<B_ * T_, 256, 0, stream>>>(x, ling, linb, xn);

    // kv projection: k row-major, v transposed to vT, vsum fused
    (void)hipMemsetAsync(vsum, 0, (size_t)B_ * S_ * 4, stream);
    gemm256_kernel<<<3072, 512, 0, stream>>>(xn, wkv_bf, k_bf, vT, vsum);

    init_slots_kernel<<<(B_ * NS * S_) / 256, 256, 0, stream>>>(si, slotsA, slotsA_bf);

    for (int it = 0; it < NIT; ++it) {
        {
            dim3 g(16, 12);
            ln_gemm_kernel<<<g, 256, 0, stream>>>(slotsA, lsg, lsb, wq_bf, nullptr,
                                                  q_bf, 768, 0);
        }
        fused_attn_kernel<<<B_ * NCHUNK, 256, 0, stream>>>(q_bf, k_bf, vT, pU, prs, avis,
                                                           (it == NIT - 1) ? 1 : 0);
        attn_reduce_kernel<<<(B_ * NS * S_) / 256, 256, 0, stream>>>(pU, prs, vsum, upd_bf);
        {
            dim3 g(16, 72);
            gru_gemm_kernel<<<g, 256, 0, stream>>>(upd_bf, slotsA_bf, gwih_bf, gwhh_bf,
                                                   gbih, gbhh, gi, gh);
        }
        gru_gates_kernel<<<(B_ * NS * S_) / 256, 256, 0, stream>>>(gi, gh, slotsA, slotsB);
        {
            dim3 g(16, 48);
            ln_gemm_kernel<<<g, 256, 0, stream>>>(slotsB, lfg, lfb, w1_bf, b1,
                                                  h1_bf, 3072, 1);
        }
        {
            dim3 g(16, 12);
            mlp2_kernel<<<g, 256, 0, stream>>>(h1_bf, w2_bf, b2, slotsB, slotsA, slotsA_bf);
        }
    }

    cluster_kernel<<<B_, 256, 0, stream>>>(slotsA, out_slots, out_mask, cm_g);
    {
        dim3 g(T_ / 256, B_);
        cattn_kernel<<<g, 256, 0, stream>>>(avis, cm_g, out_attn);
    }
}